// Round 2
// baseline (2128.023 us; speedup 1.0000x reference)
//
#include <hip/hip_runtime.h>

#define Bq 8
#define Tq 2048
#define Cq 1024
#define Hq 16
#define Nq 64
#define FFNq 3584
#define EPSq 1e-5f

typedef __bf16 bf8v __attribute__((ext_vector_type(8)));
typedef float f32x4 __attribute__((ext_vector_type(4)));

__device__ __forceinline__ unsigned short f2bf(float f) {
    unsigned u = __float_as_uint(f);
    u += 0x7fffu + ((u >> 16) & 1u);   // round-to-nearest-even
    return (unsigned short)(u >> 16);
}
__device__ __forceinline__ float bf2f(unsigned short h) {
    return __uint_as_float(((unsigned)h) << 16);
}

// ---------------- diagnostic fill (ws too small) ----------------
__global__ __launch_bounds__(256)
void diag_kernel(float* __restrict__ out, float val) {
    int i = (blockIdx.x * 256 + threadIdx.x) * 4;
    float4 v = make_float4(val, val, val, val);
    *(float4*)(out + i) = v;
}

// ---------------- fp32 -> bf16 weight conversion ----------------
__global__ __launch_bounds__(256)
void f2bf_kernel(const float* __restrict__ in, unsigned short* __restrict__ out) {
    int i = (blockIdx.x * 256 + threadIdx.x) * 4;
    float4 v = *(const float4*)(in + i);
    ushort4 o;
    o.x = f2bf(v.x); o.y = f2bf(v.y); o.z = f2bf(v.z); o.w = f2bf(v.w);
    *(ushort4*)(out + i) = o;
}

// ---------------- block reduction helper (256 threads) ----------------
__device__ __forceinline__ void blockred2(float& a, float& b, float* sm) {
#pragma unroll
    for (int m = 1; m < 64; m <<= 1) { a += __shfl_xor(a, m); b += __shfl_xor(b, m); }
    const int w = threadIdx.x >> 6;
    __syncthreads();
    if ((threadIdx.x & 63) == 0) { sm[w] = a; sm[4 + w] = b; }
    __syncthreads();
    a = sm[0] + sm[1] + sm[2] + sm[3];
    b = sm[4] + sm[5] + sm[6] + sm[7];
}

// ---------------- ln0 + ln1 fused (one block per token) ----------------
__global__ __launch_bounds__(256)
void ln01_kernel(const float* __restrict__ x,
                 const float* __restrict__ w0, const float* __restrict__ b0,
                 const float* __restrict__ w1, const float* __restrict__ b1,
                 float* __restrict__ x0, float* __restrict__ xn) {
    __shared__ float sm[8];
    const int tok = blockIdx.x, tid = threadIdx.x, c = tid * 4;
    const size_t base = (size_t)tok * Cq + c;
    float4 v = *(const float4*)(x + base);
    float s = v.x + v.y + v.z + v.w;
    float ss = v.x * v.x + v.y * v.y + v.z * v.z + v.w * v.w;
    blockred2(s, ss, sm);
    float mu = s * (1.f / Cq);
    float rstd = rsqrtf(ss * (1.f / Cq) - mu * mu + EPSq);
    float4 wv = *(const float4*)(w0 + c), bv = *(const float4*)(b0 + c);
    float4 e;
    e.x = (v.x - mu) * rstd * wv.x + bv.x;
    e.y = (v.y - mu) * rstd * wv.y + bv.y;
    e.z = (v.z - mu) * rstd * wv.z + bv.z;
    e.w = (v.w - mu) * rstd * wv.w + bv.w;
    *(float4*)(x0 + base) = e;
    s = e.x + e.y + e.z + e.w;
    ss = e.x * e.x + e.y * e.y + e.z * e.z + e.w * e.w;
    blockred2(s, ss, sm);
    mu = s * (1.f / Cq);
    rstd = rsqrtf(ss * (1.f / Cq) - mu * mu + EPSq);
    wv = *(const float4*)(w1 + c); bv = *(const float4*)(b1 + c);
    float4 o;
    o.x = (e.x - mu) * rstd * wv.x + bv.x;
    o.y = (e.y - mu) * rstd * wv.y + bv.y;
    o.z = (e.z - mu) * rstd * wv.z + bv.z;
    o.w = (e.w - mu) * rstd * wv.w + bv.w;
    *(float4*)(xn + base) = o;
}

// ---------------- single layernorm (ln2) ----------------
__global__ __launch_bounds__(256)
void ln_kernel(const float* __restrict__ x, const float* __restrict__ w,
               const float* __restrict__ b, float* __restrict__ out) {
    __shared__ float sm[8];
    const int tok = blockIdx.x, tid = threadIdx.x, c = tid * 4;
    const size_t base = (size_t)tok * Cq + c;
    float4 v = *(const float4*)(x + base);
    float s = v.x + v.y + v.z + v.w;
    float ss = v.x * v.x + v.y * v.y + v.z * v.z + v.w * v.w;
    blockred2(s, ss, sm);
    float mu = s * (1.f / Cq);
    float rstd = rsqrtf(ss * (1.f / Cq) - mu * mu + EPSq);
    float4 wv = *(const float4*)(w + c), bv = *(const float4*)(b + c);
    float4 o;
    o.x = (v.x - mu) * rstd * wv.x + bv.x;
    o.y = (v.y - mu) * rstd * wv.y + bv.y;
    o.z = (v.z - mu) * rstd * wv.z + bv.z;
    o.w = (v.w - mu) * rstd * wv.w + bv.w;
    *(float4*)(out + base) = o;
}

// ---------------- token-shift mix (single output) ----------------
__global__ __launch_bounds__(256)
void mix1_kernel(const float* __restrict__ xn, const float* __restrict__ tm,
                 ushort4* __restrict__ out) {
    const int tok = blockIdx.x, tid = threadIdx.x, c = tid * 4;
    const int t = tok & (Tq - 1);
    const size_t base = (size_t)tok * Cq + c;
    float4 xnv = *(const float4*)(xn + base);
    float4 xxv = make_float4(0.f, 0.f, 0.f, 0.f);
    if (t) xxv = *(const float4*)(xn + base - Cq);
    float4 m = *(const float4*)(tm + c);
    ushort4 o;
    o.x = f2bf(xxv.x + m.x * (xnv.x - xxv.x));
    o.y = f2bf(xxv.y + m.y * (xnv.y - xxv.y));
    o.z = f2bf(xxv.z + m.z * (xnv.z - xxv.z));
    o.w = f2bf(xxv.w + m.w * (xnv.w - xxv.w));
    out[(size_t)tok * 256 + tid] = o;
}

// ---------------- bf16 MFMA GEMM: out[m,n] = sum_k A[m,k]*W[n,k] ----------------
// MODE: 1 silu->bf16; 2 res+acc->fp32; 3 relu^2->bf16; 4 sigmoid->fp32;
//       5 res+sg*acc->fp32; 6 plain->bf16
template<int MODE>
__global__ __launch_bounds__(256, 2)
void gemm_bt(const unsigned short* __restrict__ A, const unsigned short* __restrict__ W,
             int K, int N, float* __restrict__ outF, unsigned short* __restrict__ outB,
             const float* __restrict__ res, const float* __restrict__ sg) {
    constexpr int LDT = 40;  // 32 + 8 pad (bf16 elems)
    __shared__ unsigned short As[128 * LDT];
    __shared__ unsigned short Bs[128 * LDT];
    const int tid = threadIdx.x;
    const int m0 = blockIdx.y * 128, n0 = blockIdx.x * 128;
    const int wv = tid >> 6, lane = tid & 63;
    const int wm = (wv >> 1) * 64, wn = (wv & 1) * 64;
    const int l15 = lane & 15, q = lane >> 4;

    const int srow = tid >> 1;
    const int soff = (tid & 1) * 16;
    const unsigned short* Ag = A + (size_t)(m0 + srow) * K + soff;
    const unsigned short* Wg = W + (size_t)(n0 + srow) * K + soff;
    unsigned short* Asw = &As[srow * LDT + soff];
    unsigned short* Bsw = &Bs[srow * LDT + soff];
    const unsigned short* Afr = &As[(wm + l15) * LDT + q * 8];
    const unsigned short* Bfr = &Bs[(wn + l15) * LDT + q * 8];

    f32x4 acc[4][4];
#pragma unroll
    for (int mi = 0; mi < 4; ++mi)
#pragma unroll
        for (int ni = 0; ni < 4; ++ni)
            acc[mi][ni] = {0.f, 0.f, 0.f, 0.f};

    for (int k0 = 0; k0 < K; k0 += 32) {
        uint4 a0 = *(const uint4*)(Ag + k0);
        uint4 a1 = *(const uint4*)(Ag + k0 + 8);
        uint4 b0 = *(const uint4*)(Wg + k0);
        uint4 b1 = *(const uint4*)(Wg + k0 + 8);
        __syncthreads();
        *(uint4*)Asw = a0; *(uint4*)(Asw + 8) = a1;
        *(uint4*)Bsw = b0; *(uint4*)(Bsw + 8) = b1;
        __syncthreads();
        bf8v af[4], bfv[4];
#pragma unroll
        for (int mi = 0; mi < 4; ++mi) af[mi] = *(const bf8v*)(Afr + mi * 16 * LDT);
#pragma unroll
        for (int ni = 0; ni < 4; ++ni) bfv[ni] = *(const bf8v*)(Bfr + ni * 16 * LDT);
#pragma unroll
        for (int mi = 0; mi < 4; ++mi)
#pragma unroll
            for (int ni = 0; ni < 4; ++ni)
                acc[mi][ni] = __builtin_amdgcn_mfma_f32_16x16x32_bf16(af[mi], bfv[ni], acc[mi][ni], 0, 0, 0);
    }

#pragma unroll
    for (int mi = 0; mi < 4; ++mi)
#pragma unroll
        for (int ni = 0; ni < 4; ++ni)
#pragma unroll
            for (int j = 0; j < 4; ++j) {
                const int row = m0 + wm + mi * 16 + q * 4 + j;
                const int col = n0 + wn + ni * 16 + l15;
                const size_t idx = (size_t)row * N + col;
                const float a = acc[mi][ni][j];
                if (MODE == 1) {
                    outB[idx] = f2bf(a / (1.f + __expf(-a)));
                } else if (MODE == 2) {
                    outF[idx] = res[idx] + a;
                } else if (MODE == 3) {
                    float t = fmaxf(a, 0.f);
                    outB[idx] = f2bf(t * t);
                } else if (MODE == 4) {
                    outF[idx] = 1.f / (1.f + __expf(-a));
                } else if (MODE == 5) {
                    outF[idx] = res[idx] + sg[idx] * a;
                } else {
                    outB[idx] = f2bf(a);
                }
            }
}

// ---------------- WKV5 recurrence (bf16 r/k/v in, fp32 y out) ----------------
// grid = B*H blocks, 256 threads (4 waves). Wave w owns state rows i in [16w,16w+16),
// lane j owns column j. Partial y combined through LDS every 32 steps.
__global__ __launch_bounds__(256)
void wkv_kernel(const unsigned short* __restrict__ r, const unsigned short* __restrict__ k,
                const unsigned short* __restrict__ v, const float* __restrict__ decay,
                const float* __restrict__ faaaa, float* __restrict__ y) {
    __shared__ float rs[32][64], ks[32][64], yp[4][32][64];
    const int bh = blockIdx.x;
    const int b = bh >> 4, h = bh & 15;
    const int wv = threadIdx.x >> 6, j = threadIdx.x & 63;
    const int i0 = wv * 16;
    float S[16], ew[16];
#pragma unroll
    for (int ii = 0; ii < 16; ++ii) {
        S[ii] = 0.f;
        ew[ii] = expf(-expf(decay[h * Nq + i0 + ii]));
    }
    const float uj = faaaa[h * Nq + j];
    const size_t basebh = (size_t)b * Tq * Cq + (size_t)h * Nq;

    const int ltl = threadIdx.x >> 3;        // token-in-tile 0..31
    const int lci = (threadIdx.x & 7) * 8;   // channel 0..56

    for (int t0 = 0; t0 < Tq; t0 += 32) {
        const unsigned short* rp = r + basebh + (size_t)(t0 + ltl) * Cq + lci;
        const unsigned short* kp = k + basebh + (size_t)(t0 + ltl) * Cq + lci;
        uint4 ru = *(const uint4*)rp;
        uint4 ku = *(const uint4*)kp;
        float* rd = &rs[ltl][lci];
        float* kd = &ks[ltl][lci];
        rd[0] = bf2f((unsigned short)(ru.x & 0xffff)); rd[1] = bf2f((unsigned short)(ru.x >> 16));
        rd[2] = bf2f((unsigned short)(ru.y & 0xffff)); rd[3] = bf2f((unsigned short)(ru.y >> 16));
        rd[4] = bf2f((unsigned short)(ru.z & 0xffff)); rd[5] = bf2f((unsigned short)(ru.z >> 16));
        rd[6] = bf2f((unsigned short)(ru.w & 0xffff)); rd[7] = bf2f((unsigned short)(ru.w >> 16));
        kd[0] = bf2f((unsigned short)(ku.x & 0xffff)); kd[1] = bf2f((unsigned short)(ku.x >> 16));
        kd[2] = bf2f((unsigned short)(ku.y & 0xffff)); kd[3] = bf2f((unsigned short)(ku.y >> 16));
        kd[4] = bf2f((unsigned short)(ku.z & 0xffff)); kd[5] = bf2f((unsigned short)(ku.z >> 16));
        kd[6] = bf2f((unsigned short)(ku.w & 0xffff)); kd[7] = bf2f((unsigned short)(ku.w >> 16));
        __syncthreads();
        for (int tl = 0; tl < 32; ++tl) {
            const float vj = bf2f(v[basebh + (size_t)(t0 + tl) * Cq + j]);
            const float4* r4 = (const float4*)&rs[tl][i0];
            const float4* k4 = (const float4*)&ks[tl][i0];
            float yv = 0.f;
#pragma unroll
            for (int q4 = 0; q4 < 4; ++q4) {
                float4 rr = r4[q4], kk = k4[q4];
                const int bi = q4 * 4;
                yv += rr.x * S[bi + 0]; S[bi + 0] = ew[bi + 0] * S[bi + 0] + kk.x * vj;
                yv += rr.y * S[bi + 1]; S[bi + 1] = ew[bi + 1] * S[bi + 1] + kk.y * vj;
                yv += rr.z * S[bi + 2]; S[bi + 2] = ew[bi + 2] * S[bi + 2] + kk.z * vj;
                yv += rr.w * S[bi + 3]; S[bi + 3] = ew[bi + 3] * S[bi + 3] + kk.w * vj;
            }
            if (wv == 0) {  // u-diagonal rank-1 term: (sum_i r_i u_i k_i) * v_j
                float p = rs[tl][j] * uj * ks[tl][j];
#pragma unroll
                for (int m = 1; m < 64; m <<= 1) p += __shfl_xor(p, m);
                yv += p * vj;
            }
            yp[wv][tl][j] = yv;
        }
        __syncthreads();
#pragma unroll
        for (int qq = 0; qq < 8; ++qq) {
            const int tl = wv * 8 + qq;
            float s = yp[0][tl][j] + yp[1][tl][j] + yp[2][tl][j] + yp[3][tl][j];
            y[basebh + (size_t)(t0 + tl) * Cq + j] = s;
        }
        __syncthreads();
    }
}

// ---------------- GroupNorm(y/8) * lnx_w + lnx_b, then * silu-gate g -> bf16 ----------------
__global__ __launch_bounds__(256)
void gnmul_kernel(const float* __restrict__ y, const float* __restrict__ lw,
                  const float* __restrict__ lb, const unsigned short* __restrict__ g,
                  ushort4* __restrict__ ao) {
    const int tok = blockIdx.x, tid = threadIdx.x, c = tid * 4;
    const size_t base = (size_t)tok * Cq + c;
    float4 v = *(const float4*)(y + base);
    v.x *= 0.125f; v.y *= 0.125f; v.z *= 0.125f; v.w *= 0.125f;
    float s = v.x + v.y + v.z + v.w;
    float ss = v.x * v.x + v.y * v.y + v.z * v.z + v.w * v.w;
#pragma unroll
    for (int m = 1; m < 16; m <<= 1) { s += __shfl_xor(s, m); ss += __shfl_xor(ss, m); }
    const float mu = s * (1.f / Nq);
    const float rstd = rsqrtf(ss * (1.f / Nq) - mu * mu + EPSq);
    float4 wv = *(const float4*)(lw + c), bv = *(const float4*)(lb + c);
    ushort4 gv = *(const ushort4*)(g + base);
    ushort4 o;
    o.x = f2bf(((v.x - mu) * rstd * wv.x + bv.x) * bf2f(gv.x));
    o.y = f2bf(((v.y - mu) * rstd * wv.y + bv.y) * bf2f(gv.y));
    o.z = f2bf(((v.z - mu) * rstd * wv.z + bv.z) * bf2f(gv.z));
    o.w = f2bf(((v.w - mu) * rstd * wv.w + bv.w) * bf2f(gv.w));
    ao[(size_t)tok * 256 + tid] = o;
}

// ---------------- launcher ----------------
extern "C" void kernel_launch(void* const* d_in, const int* in_sizes, int n_in,
                              void* d_out, int out_size, void* d_ws, size_t ws_size,
                              hipStream_t stream) {
    const float* x     = (const float*)d_in[0];
    const float* ln0w  = (const float*)d_in[1];
    const float* ln0b  = (const float*)d_in[2];
    const float* ln1w  = (const float*)d_in[3];
    const float* ln1b  = (const float*)d_in[4];
    const float* ln2w  = (const float*)d_in[5];
    const float* ln2b  = (const float*)d_in[6];
    const float* atmk  = (const float*)d_in[7];
    const float* atmv  = (const float*)d_in[8];
    const float* atmr  = (const float*)d_in[9];
    const float* atmg  = (const float*)d_in[10];
    const float* decay = (const float*)d_in[11];
    const float* faaaa = (const float*)d_in[12];
    const float* aWr   = (const float*)d_in[13];
    const float* aWk   = (const float*)d_in[14];
    const float* aWv   = (const float*)d_in[15];
    const float* aWg   = (const float*)d_in[16];
    const float* aWo   = (const float*)d_in[17];
    const float* lnxw  = (const float*)d_in[18];
    const float* lnxb  = (const float*)d_in[19];
    const float* ftmk  = (const float*)d_in[20];
    const float* ftmr  = (const float*)d_in[21];
    const float* fWk   = (const float*)d_in[22];
    const float* fWr   = (const float*)d_in[23];
    const float* fWv   = (const float*)d_in[24];

    const size_t MB = 1024ull * 1024ull;
    const size_t WS_NEEDED = 250 * MB;
    dim3 blk(256);

    if (ws_size < WS_NEEDED) {
        // diagnostic: fill output with 1000 + ws_MB so the absmax report tells us ws_size
        diag_kernel<<<out_size / 1024, blk, 0, stream>>>((float*)d_out,
            1000.f + (float)((double)ws_size / (double)MB));
        return;
    }

    char* ws = (char*)d_ws;
    // weights (bf16): 26 MB total
    unsigned short* WR  = (unsigned short*)(ws + 0 * MB);
    unsigned short* WK  = (unsigned short*)(ws + 2 * MB);
    unsigned short* WV  = (unsigned short*)(ws + 4 * MB);
    unsigned short* WG  = (unsigned short*)(ws + 6 * MB);
    unsigned short* WO  = (unsigned short*)(ws + 8 * MB);
    unsigned short* FWK = (unsigned short*)(ws + 10 * MB);
    unsigned short* FWR = (unsigned short*)(ws + 17 * MB);
    unsigned short* FWV = (unsigned short*)(ws + 19 * MB);
    // activations
    float*          XN  = (float*)(ws + 26 * MB);           // xn -> y -> xn2 -> SR
    unsigned short* MIX = (unsigned short*)(ws + 90 * MB);  // xk/xv/xr/xg -> Ao -> xk2/xr2
    unsigned short* Rb  = (unsigned short*)(ws + 122 * MB);
    unsigned short* Kb  = (unsigned short*)(ws + 154 * MB);
    unsigned short* Vb  = (unsigned short*)(ws + 186 * MB);
    unsigned short* Gb  = (unsigned short*)(ws + 218 * MB); // ends at 250 MB
    unsigned short* KF  = (unsigned short*)(ws + 122 * MB); // 112 MB, reuses Rb..Gb (dead)
    float*          SR  = (float*)(ws + 26 * MB);           // reuses XN (dead)
    float*          X0  = (float*)d_out;                    // residual stream lives in d_out
    float*          Y   = (float*)(ws + 26 * MB);           // wkv out, reuses XN (dead)

    const int NTOK = Bq * Tq;  // 16384
    dim3 g8(8, 128), g28(28, 128);

    // weights -> bf16
    f2bf_kernel<<<1024, blk, 0, stream>>>(aWr, WR);
    f2bf_kernel<<<1024, blk, 0, stream>>>(aWk, WK);
    f2bf_kernel<<<1024, blk, 0, stream>>>(aWv, WV);
    f2bf_kernel<<<1024, blk, 0, stream>>>(aWg, WG);
    f2bf_kernel<<<1024, blk, 0, stream>>>(aWo, WO);
    f2bf_kernel<<<3584, blk, 0, stream>>>(fWk, FWK);
    f2bf_kernel<<<1024, blk, 0, stream>>>(fWr, FWR);
    f2bf_kernel<<<3584, blk, 0, stream>>>(fWv, FWV);

    // ln0 + ln1: x -> X0 (=d_out), xn -> XN
    ln01_kernel<<<NTOK, blk, 0, stream>>>(x, ln0w, ln0b, ln1w, ln1b, X0, XN);

    // time-mix projections (shared MIX buffer, sequential)
    mix1_kernel<<<NTOK, blk, 0, stream>>>(XN, atmr, (ushort4*)MIX);
    gemm_bt<6><<<g8, blk, 0, stream>>>(MIX, WR, Cq, Cq, nullptr, Rb, nullptr, nullptr);
    mix1_kernel<<<NTOK, blk, 0, stream>>>(XN, atmk, (ushort4*)MIX);
    gemm_bt<6><<<g8, blk, 0, stream>>>(MIX, WK, Cq, Cq, nullptr, Kb, nullptr, nullptr);
    mix1_kernel<<<NTOK, blk, 0, stream>>>(XN, atmv, (ushort4*)MIX);
    gemm_bt<6><<<g8, blk, 0, stream>>>(MIX, WV, Cq, Cq, nullptr, Vb, nullptr, nullptr);
    mix1_kernel<<<NTOK, blk, 0, stream>>>(XN, atmg, (ushort4*)MIX);
    gemm_bt<1><<<g8, blk, 0, stream>>>(MIX, WG, Cq, Cq, nullptr, Gb, nullptr, nullptr);

    // wkv recurrence -> Y (xn dead)
    wkv_kernel<<<Bq * Hq, blk, 0, stream>>>(Rb, Kb, Vb, decay, faaaa, Y);
    // groupnorm(y/8)*silu-gate -> Ao (bf16, into MIX)
    gnmul_kernel<<<NTOK, blk, 0, stream>>>(Y, lnxw, lnxb, Gb, (ushort4*)MIX);
    // Wo projection + residual: X0 += Ao @ Wo^T
    gemm_bt<2><<<g8, blk, 0, stream>>>(MIX, WO, Cq, Cq, X0, nullptr, X0, nullptr);

    // channel-mix
    ln_kernel<<<NTOK, blk, 0, stream>>>(X0, ln2w, ln2b, XN);
    mix1_kernel<<<NTOK, blk, 0, stream>>>(XN, ftmk, (ushort4*)MIX);
    gemm_bt<3><<<g28, blk, 0, stream>>>(MIX, FWK, Cq, FFNq, nullptr, KF, nullptr, nullptr);
    mix1_kernel<<<NTOK, blk, 0, stream>>>(XN, ftmr, (ushort4*)MIX);
    gemm_bt<4><<<g8, blk, 0, stream>>>(MIX, FWR, Cq, Cq, SR, nullptr, nullptr, nullptr);
    gemm_bt<5><<<g8, blk, 0, stream>>>(KF, FWV, FFNq, Cq, X0, nullptr, X0, SR);
}

// Round 3
// 1154.441 us; speedup vs baseline: 1.8433x; 1.8433x over previous
//
#include <hip/hip_runtime.h>

#define Bq 8
#define Tq 2048
#define Cq 1024
#define Hq 16
#define Nq 64
#define FFNq 3584
#define EPSq 1e-5f

typedef __bf16 bf8v __attribute__((ext_vector_type(8)));
typedef float f32x4 __attribute__((ext_vector_type(4)));

typedef __attribute__((address_space(1))) const unsigned int GU;
typedef __attribute__((address_space(3))) unsigned int LU;

__device__ __forceinline__ void gload16(const unsigned short* g, unsigned short* l) {
    __builtin_amdgcn_global_load_lds((GU*)g, (LU*)l, 16, 0, 0);
}

__device__ __forceinline__ unsigned short f2bf(float f) {
    unsigned u = __float_as_uint(f);
    u += 0x7fffu + ((u >> 16) & 1u);   // round-to-nearest-even
    return (unsigned short)(u >> 16);
}
__device__ __forceinline__ float bf2f(unsigned short h) {
    return __uint_as_float(((unsigned)h) << 16);
}

// ---------------- diagnostic fill (ws too small) ----------------
__global__ __launch_bounds__(256)
void diag_kernel(float* __restrict__ out, float val) {
    int i = (blockIdx.x * 256 + threadIdx.x) * 4;
    float4 v = make_float4(val, val, val, val);
    *(float4*)(out + i) = v;
}

// ---------------- fp32 -> bf16 weight conversion ----------------
__global__ __launch_bounds__(256)
void f2bf_kernel(const float* __restrict__ in, unsigned short* __restrict__ out) {
    int i = (blockIdx.x * 256 + threadIdx.x) * 4;
    float4 v = *(const float4*)(in + i);
    ushort4 o;
    o.x = f2bf(v.x); o.y = f2bf(v.y); o.z = f2bf(v.z); o.w = f2bf(v.w);
    *(ushort4*)(out + i) = o;
}

// ---------------- block reduction helper (256 threads) ----------------
__device__ __forceinline__ void blockred2(float& a, float& b, float* sm) {
#pragma unroll
    for (int m = 1; m < 64; m <<= 1) { a += __shfl_xor(a, m); b += __shfl_xor(b, m); }
    const int w = threadIdx.x >> 6;
    __syncthreads();
    if ((threadIdx.x & 63) == 0) { sm[w] = a; sm[4 + w] = b; }
    __syncthreads();
    a = sm[0] + sm[1] + sm[2] + sm[3];
    b = sm[4] + sm[5] + sm[6] + sm[7];
}

// ---------------- ln0 + ln1 fused (one block per token) ----------------
__global__ __launch_bounds__(256)
void ln01_kernel(const float* __restrict__ x,
                 const float* __restrict__ w0, const float* __restrict__ b0,
                 const float* __restrict__ w1, const float* __restrict__ b1,
                 float* __restrict__ x0, float* __restrict__ xn) {
    __shared__ float sm[8];
    const int tok = blockIdx.x, tid = threadIdx.x, c = tid * 4;
    const size_t base = (size_t)tok * Cq + c;
    float4 v = *(const float4*)(x + base);
    float s = v.x + v.y + v.z + v.w;
    float ss = v.x * v.x + v.y * v.y + v.z * v.z + v.w * v.w;
    blockred2(s, ss, sm);
    float mu = s * (1.f / Cq);
    float rstd = rsqrtf(ss * (1.f / Cq) - mu * mu + EPSq);
    float4 wv = *(const float4*)(w0 + c), bv = *(const float4*)(b0 + c);
    float4 e;
    e.x = (v.x - mu) * rstd * wv.x + bv.x;
    e.y = (v.y - mu) * rstd * wv.y + bv.y;
    e.z = (v.z - mu) * rstd * wv.z + bv.z;
    e.w = (v.w - mu) * rstd * wv.w + bv.w;
    *(float4*)(x0 + base) = e;
    s = e.x + e.y + e.z + e.w;
    ss = e.x * e.x + e.y * e.y + e.z * e.z + e.w * e.w;
    blockred2(s, ss, sm);
    mu = s * (1.f / Cq);
    rstd = rsqrtf(ss * (1.f / Cq) - mu * mu + EPSq);
    wv = *(const float4*)(w1 + c); bv = *(const float4*)(b1 + c);
    float4 o;
    o.x = (e.x - mu) * rstd * wv.x + bv.x;
    o.y = (e.y - mu) * rstd * wv.y + bv.y;
    o.z = (e.z - mu) * rstd * wv.z + bv.z;
    o.w = (e.w - mu) * rstd * wv.w + bv.w;
    *(float4*)(xn + base) = o;
}

// ---------------- single layernorm (ln2) ----------------
__global__ __launch_bounds__(256)
void ln_kernel(const float* __restrict__ x, const float* __restrict__ w,
               const float* __restrict__ b, float* __restrict__ out) {
    __shared__ float sm[8];
    const int tok = blockIdx.x, tid = threadIdx.x, c = tid * 4;
    const size_t base = (size_t)tok * Cq + c;
    float4 v = *(const float4*)(x + base);
    float s = v.x + v.y + v.z + v.w;
    float ss = v.x * v.x + v.y * v.y + v.z * v.z + v.w * v.w;
    blockred2(s, ss, sm);
    float mu = s * (1.f / Cq);
    float rstd = rsqrtf(ss * (1.f / Cq) - mu * mu + EPSq);
    float4 wv = *(const float4*)(w + c), bv = *(const float4*)(b + c);
    float4 o;
    o.x = (v.x - mu) * rstd * wv.x + bv.x;
    o.y = (v.y - mu) * rstd * wv.y + bv.y;
    o.z = (v.z - mu) * rstd * wv.z + bv.z;
    o.w = (v.w - mu) * rstd * wv.w + bv.w;
    *(float4*)(out + base) = o;
}

// ---------------- token-shift mix (single output) ----------------
__global__ __launch_bounds__(256)
void mix1_kernel(const float* __restrict__ xn, const float* __restrict__ tm,
                 ushort4* __restrict__ out) {
    const int tok = blockIdx.x, tid = threadIdx.x, c = tid * 4;
    const int t = tok & (Tq - 1);
    const size_t base = (size_t)tok * Cq + c;
    float4 xnv = *(const float4*)(xn + base);
    float4 xxv = make_float4(0.f, 0.f, 0.f, 0.f);
    if (t) xxv = *(const float4*)(xn + base - Cq);
    float4 m = *(const float4*)(tm + c);
    ushort4 o;
    o.x = f2bf(xxv.x + m.x * (xnv.x - xxv.x));
    o.y = f2bf(xxv.y + m.y * (xnv.y - xxv.y));
    o.z = f2bf(xxv.z + m.z * (xnv.z - xxv.z));
    o.w = f2bf(xxv.w + m.w * (xnv.w - xxv.w));
    out[(size_t)tok * 256 + tid] = o;
}

// ---------------- bf16 MFMA GEMM (m97 pattern): out[m,n] = sum_k A[m,k]*W[n,k] ----
// MODE: 1 silu->bf16; 2 res+acc->fp32; 3 relu^2->bf16; 4 sigmoid->fp32;
//       5 res+sg*acc->fp32; 6 plain->bf16
template<int MODE>
__global__ __launch_bounds__(256, 2)
void gemm_bt(const unsigned short* __restrict__ A, const unsigned short* __restrict__ W,
             int K, int N, float* __restrict__ outF, unsigned short* __restrict__ outB,
             const float* __restrict__ res, const float* __restrict__ sg) {
    __shared__ unsigned short As[128 * 32];
    __shared__ unsigned short Bs[128 * 32];
    const int tid = threadIdx.x;
    const int m0 = blockIdx.y * 128, n0 = blockIdx.x * 128;
    const int wv = tid >> 6, lane = tid & 63;
    const int wm = (wv >> 1) * 64, wn = (wv & 1) * 64;
    const int l15 = lane & 15, q = lane >> 4;

    // global_load_lds staging: wave wv covers tile rows [wv*32, wv*32+32), 2 calls of 16 rows.
    // lane l -> LDS base + l*16B == row l/4 (64B rows), col (l&3)*16B; source must match.
    const int srow = wv * 32 + (lane >> 2);
    const int scol = (lane & 3) * 8;
    const unsigned short* Ag0 = A + (size_t)(m0 + srow) * K + scol;
    const unsigned short* Ag1 = A + (size_t)(m0 + srow + 16) * K + scol;
    const unsigned short* Wg0 = W + (size_t)(n0 + srow) * K + scol;
    const unsigned short* Wg1 = W + (size_t)(n0 + srow + 16) * K + scol;
    unsigned short* As0 = &As[(wv * 32) * 32];
    unsigned short* As1 = &As[(wv * 32 + 16) * 32];
    unsigned short* Bs0 = &Bs[(wv * 32) * 32];
    unsigned short* Bs1 = &Bs[(wv * 32 + 16) * 32];

    f32x4 acc[4][4];
#pragma unroll
    for (int mi = 0; mi < 4; ++mi)
#pragma unroll
        for (int ni = 0; ni < 4; ++ni)
            acc[mi][ni] = {0.f, 0.f, 0.f, 0.f};

    for (int k0 = 0; k0 < K; k0 += 32) {
        gload16(Ag0 + k0, As0);
        gload16(Ag1 + k0, As1);
        gload16(Wg0 + k0, Bs0);
        gload16(Wg1 + k0, Bs1);
        __syncthreads();
        bf8v af[4], bfv[4];
#pragma unroll
        for (int mi = 0; mi < 4; ++mi) af[mi] = *(const bf8v*)&As[(wm + mi * 16 + l15) * 32 + q * 8];
#pragma unroll
        for (int ni = 0; ni < 4; ++ni) bfv[ni] = *(const bf8v*)&Bs[(wn + ni * 16 + l15) * 32 + q * 8];
#pragma unroll
        for (int mi = 0; mi < 4; ++mi)
#pragma unroll
            for (int ni = 0; ni < 4; ++ni)
                acc[mi][ni] = __builtin_amdgcn_mfma_f32_16x16x32_bf16(af[mi], bfv[ni], acc[mi][ni], 0, 0, 0);
        __syncthreads();
    }

#pragma unroll
    for (int mi = 0; mi < 4; ++mi)
#pragma unroll
        for (int ni = 0; ni < 4; ++ni)
#pragma unroll
            for (int j = 0; j < 4; ++j) {
                const int row = m0 + wm + mi * 16 + q * 4 + j;
                const int col = n0 + wn + ni * 16 + l15;
                const size_t idx = (size_t)row * N + col;
                const float a = acc[mi][ni][j];
                if (MODE == 1) {
                    outB[idx] = f2bf(a / (1.f + __expf(-a)));
                } else if (MODE == 2) {
                    outF[idx] = res[idx] + a;
                } else if (MODE == 3) {
                    float t = fmaxf(a, 0.f);
                    outB[idx] = f2bf(t * t);
                } else if (MODE == 4) {
                    outF[idx] = 1.f / (1.f + __expf(-a));
                } else if (MODE == 5) {
                    outF[idx] = res[idx] + sg[idx] * a;
                } else {
                    outB[idx] = f2bf(a);
                }
            }
}

// ---------------- WKV5: chunked linear attention, MFMA ----------------
// One block per (b,h); 4 waves; chunk L=64; state S (64x64 fp32) in registers,
// carried across 32 chunks. Per chunk:
//   rp[t,i]=r*ew^t, km[s,i]=k*ew^-(s+1), kd[s,i]=k*ew^(63-s)
//   A = tril(rp.km^T, -1) + diag(D), D[t]=sum_i r u k
//   Y = A.V + rp.Sc ; S = ew^64*S + kd^T.V
__global__ __launch_bounds__(256)
void wkv_kernel(const unsigned short* __restrict__ r, const unsigned short* __restrict__ k,
                const unsigned short* __restrict__ v, const float* __restrict__ decay,
                const float* __restrict__ faaaa, float* __restrict__ y) {
    __shared__ unsigned short rp[64 * 72], km[64 * 72], kdT[64 * 72];
    __shared__ unsigned short VT[64 * 72], Abf[64 * 72], ScT[64 * 72];
    __shared__ float Dt[64];
    const int tid = threadIdx.x;
    const int bh = blockIdx.x, b = bh >> 4, h = bh & 15;
    // elementwise-phase mapping: token row tr, 16-col group g4
    const int tr = tid >> 2, g4 = tid & 3, i0 = g4 * 16;
    // mfma mapping
    const int wv = tid >> 6, lane = tid & 63, l15 = lane & 15, q = lane >> 4;
    const float LOG2E = 1.44269504088896340736f;

    float l2w[16], uu[16];
#pragma unroll
    for (int ii = 0; ii < 16; ++ii) {
        l2w[ii] = -__expf(decay[h * Nq + i0 + ii]) * LOG2E;
        uu[ii] = faaaa[h * Nq + i0 + ii];
    }
    float ewL[4];
#pragma unroll
    for (int jr = 0; jr < 4; ++jr) {
        float lw = -__expf(decay[h * Nq + 16 * wv + q * 4 + jr]) * LOG2E;
        ewL[jr] = exp2f(64.f * lw);
    }
    f32x4 S[4];
#pragma unroll
    for (int nt = 0; nt < 4; ++nt) S[nt] = {0.f, 0.f, 0.f, 0.f};
    for (int idx = tid; idx < 64 * 72; idx += 256) ScT[idx] = 0;
    __syncthreads();

    const size_t rowbase = (size_t)b * Tq;
    const int colbase = h * Nq;

    for (int c = 0; c < 32; ++c) {
        // ---- elementwise: load r/k/v rows, build scaled operands ----
        const size_t grow = (rowbase + c * 64 + tr) * Cq + colbase + i0;
        unsigned short rs_[16], ks_[16], vs_[16];
        *(uint4*)&rs_[0] = *(const uint4*)(r + grow);
        *(uint4*)&rs_[8] = *(const uint4*)(r + grow + 8);
        *(uint4*)&ks_[0] = *(const uint4*)(k + grow);
        *(uint4*)&ks_[8] = *(const uint4*)(k + grow + 8);
        *(uint4*)&vs_[0] = *(const uint4*)(v + grow);
        *(uint4*)&vs_[8] = *(const uint4*)(v + grow + 8);
        float pd = 0.f;
        const float ftr = (float)tr;
#pragma unroll
        for (int ii = 0; ii < 16; ++ii) {
            float rf = bf2f(rs_[ii]), kf = bf2f(ks_[ii]);
            rp[tr * 72 + i0 + ii] = f2bf(rf * exp2f(ftr * l2w[ii]));
            km[tr * 72 + i0 + ii] = f2bf(kf * exp2f(-(ftr + 1.f) * l2w[ii]));
            kdT[(i0 + ii) * 72 + tr] = f2bf(kf * exp2f((63.f - ftr) * l2w[ii]));
            VT[(i0 + ii) * 72 + tr] = vs_[ii];
            pd += rf * uu[ii] * kf;
        }
        pd += __shfl_xor(pd, 1);
        pd += __shfl_xor(pd, 2);
        if (g4 == 0) Dt[tr] = pd;
        __syncthreads();

        // ---- phase A: A_raw = rp . km^T, mask+diag -> Abf (rows owned by wave) ----
        f32x4 accA[4];
#pragma unroll
        for (int nt = 0; nt < 4; ++nt) accA[nt] = {0.f, 0.f, 0.f, 0.f};
#pragma unroll
        for (int ks = 0; ks < 2; ++ks) {
            bf8v a = *(const bf8v*)&rp[(16 * wv + l15) * 72 + ks * 32 + q * 8];
#pragma unroll
            for (int nt = 0; nt < 4; ++nt) {
                bf8v bb = *(const bf8v*)&km[(16 * nt + l15) * 72 + ks * 32 + q * 8];
                accA[nt] = __builtin_amdgcn_mfma_f32_16x16x32_bf16(a, bb, accA[nt], 0, 0, 0);
            }
        }
#pragma unroll
        for (int nt = 0; nt < 4; ++nt)
#pragma unroll
            for (int jr = 0; jr < 4; ++jr) {
                const int t = 16 * wv + q * 4 + jr, s = 16 * nt + l15;
                const float a = accA[nt][jr];
                const float val = (s < t) ? a : ((s == t) ? Dt[t] : 0.f);
                Abf[t * 72 + s] = f2bf(val);
            }
        // no barrier needed: each wave reads back exactly the Abf rows it wrote

        // ---- phase B: Y = Abf.V + rp.Sc ----
        f32x4 accY[4];
#pragma unroll
        for (int nt = 0; nt < 4; ++nt) accY[nt] = {0.f, 0.f, 0.f, 0.f};
#pragma unroll
        for (int ks = 0; ks < 2; ++ks) {
            bf8v a = *(const bf8v*)&Abf[(16 * wv + l15) * 72 + ks * 32 + q * 8];
#pragma unroll
            for (int nt = 0; nt < 4; ++nt) {
                bf8v bb = *(const bf8v*)&VT[(16 * nt + l15) * 72 + ks * 32 + q * 8];
                accY[nt] = __builtin_amdgcn_mfma_f32_16x16x32_bf16(a, bb, accY[nt], 0, 0, 0);
            }
        }
#pragma unroll
        for (int ks = 0; ks < 2; ++ks) {
            bf8v a = *(const bf8v*)&rp[(16 * wv + l15) * 72 + ks * 32 + q * 8];
#pragma unroll
            for (int nt = 0; nt < 4; ++nt) {
                bf8v bb = *(const bf8v*)&ScT[(16 * nt + l15) * 72 + ks * 32 + q * 8];
                accY[nt] = __builtin_amdgcn_mfma_f32_16x16x32_bf16(a, bb, accY[nt], 0, 0, 0);
            }
        }
#pragma unroll
        for (int nt = 0; nt < 4; ++nt)
#pragma unroll
            for (int jr = 0; jr < 4; ++jr) {
                const int t = 16 * wv + q * 4 + jr, j = 16 * nt + l15;
                y[(rowbase + c * 64 + t) * Cq + colbase + j] = accY[nt][jr];
            }

        // ---- phase C: U = kdT . V ; state update ----
        f32x4 accU[4];
#pragma unroll
        for (int nt = 0; nt < 4; ++nt) accU[nt] = {0.f, 0.f, 0.f, 0.f};
#pragma unroll
        for (int ks = 0; ks < 2; ++ks) {
            bf8v a = *(const bf8v*)&kdT[(16 * wv + l15) * 72 + ks * 32 + q * 8];
#pragma unroll
            for (int nt = 0; nt < 4; ++nt) {
                bf8v bb = *(const bf8v*)&VT[(16 * nt + l15) * 72 + ks * 32 + q * 8];
                accU[nt] = __builtin_amdgcn_mfma_f32_16x16x32_bf16(a, bb, accU[nt], 0, 0, 0);
            }
        }
        __syncthreads();  // all waves done reading ScT (phase B) before overwrite
#pragma unroll
        for (int nt = 0; nt < 4; ++nt) {
#pragma unroll
            for (int jr = 0; jr < 4; ++jr)
                S[nt][jr] = ewL[jr] * S[nt][jr] + accU[nt][jr];
            ushort4 sc;
            sc.x = f2bf(S[nt][0]); sc.y = f2bf(S[nt][1]);
            sc.z = f2bf(S[nt][2]); sc.w = f2bf(S[nt][3]);
            // ScT[j][i]: j = 16nt+l15, i = 16wv + 4q + jr (4 consecutive)
            *(ushort4*)&ScT[(16 * nt + l15) * 72 + 16 * wv + q * 4] = sc;
        }
        __syncthreads();  // ScT + operand buffers safe for next chunk
    }
}

// ---------------- GroupNorm(y/8) * lnx_w + lnx_b, then * silu-gate g -> bf16 ----------------
__global__ __launch_bounds__(256)
void gnmul_kernel(const float* __restrict__ y, const float* __restrict__ lw,
                  const float* __restrict__ lb, const unsigned short* __restrict__ g,
                  ushort4* __restrict__ ao) {
    const int tok = blockIdx.x, tid = threadIdx.x, c = tid * 4;
    const size_t base = (size_t)tok * Cq + c;
    float4 v = *(const float4*)(y + base);
    v.x *= 0.125f; v.y *= 0.125f; v.z *= 0.125f; v.w *= 0.125f;
    float s = v.x + v.y + v.z + v.w;
    float ss = v.x * v.x + v.y * v.y + v.z * v.z + v.w * v.w;
#pragma unroll
    for (int m = 1; m < 16; m <<= 1) { s += __shfl_xor(s, m); ss += __shfl_xor(ss, m); }
    const float mu = s * (1.f / Nq);
    const float rstd = rsqrtf(ss * (1.f / Nq) - mu * mu + EPSq);
    float4 wv = *(const float4*)(lw + c), bv = *(const float4*)(lb + c);
    ushort4 gv = *(const ushort4*)(g + base);
    ushort4 o;
    o.x = f2bf(((v.x - mu) * rstd * wv.x + bv.x) * bf2f(gv.x));
    o.y = f2bf(((v.y - mu) * rstd * wv.y + bv.y) * bf2f(gv.y));
    o.z = f2bf(((v.z - mu) * rstd * wv.z + bv.z) * bf2f(gv.z));
    o.w = f2bf(((v.w - mu) * rstd * wv.w + bv.w) * bf2f(gv.w));
    ao[(size_t)tok * 256 + tid] = o;
}

// ---------------- launcher ----------------
extern "C" void kernel_launch(void* const* d_in, const int* in_sizes, int n_in,
                              void* d_out, int out_size, void* d_ws, size_t ws_size,
                              hipStream_t stream) {
    const float* x     = (const float*)d_in[0];
    const float* ln0w  = (const float*)d_in[1];
    const float* ln0b  = (const float*)d_in[2];
    const float* ln1w  = (const float*)d_in[3];
    const float* ln1b  = (const float*)d_in[4];
    const float* ln2w  = (const float*)d_in[5];
    const float* ln2b  = (const float*)d_in[6];
    const float* atmk  = (const float*)d_in[7];
    const float* atmv  = (const float*)d_in[8];
    const float* atmr  = (const float*)d_in[9];
    const float* atmg  = (const float*)d_in[10];
    const float* decay = (const float*)d_in[11];
    const float* faaaa = (const float*)d_in[12];
    const float* aWr   = (const float*)d_in[13];
    const float* aWk   = (const float*)d_in[14];
    const float* aWv   = (const float*)d_in[15];
    const float* aWg   = (const float*)d_in[16];
    const float* aWo   = (const float*)d_in[17];
    const float* lnxw  = (const float*)d_in[18];
    const float* lnxb  = (const float*)d_in[19];
    const float* ftmk  = (const float*)d_in[20];
    const float* ftmr  = (const float*)d_in[21];
    const float* fWk   = (const float*)d_in[22];
    const float* fWr   = (const float*)d_in[23];
    const float* fWv   = (const float*)d_in[24];

    const size_t MB = 1024ull * 1024ull;
    const size_t WS_NEEDED = 250 * MB;
    dim3 blk(256);

    if (ws_size < WS_NEEDED) {
        diag_kernel<<<out_size / 1024, blk, 0, stream>>>((float*)d_out,
            1000.f + (float)((double)ws_size / (double)MB));
        return;
    }

    char* ws = (char*)d_ws;
    // weights (bf16): 26 MB total
    unsigned short* WR  = (unsigned short*)(ws + 0 * MB);
    unsigned short* WK  = (unsigned short*)(ws + 2 * MB);
    unsigned short* WV  = (unsigned short*)(ws + 4 * MB);
    unsigned short* WG  = (unsigned short*)(ws + 6 * MB);
    unsigned short* WO  = (unsigned short*)(ws + 8 * MB);
    unsigned short* FWK = (unsigned short*)(ws + 10 * MB);
    unsigned short* FWR = (unsigned short*)(ws + 17 * MB);
    unsigned short* FWV = (unsigned short*)(ws + 19 * MB);
    // activations
    float*          XN  = (float*)(ws + 26 * MB);           // xn -> y -> xn2 -> SR
    unsigned short* MIX = (unsigned short*)(ws + 90 * MB);  // xk/xv/xr/xg -> Ao -> xk2/xr2
    unsigned short* Rb  = (unsigned short*)(ws + 122 * MB);
    unsigned short* Kb  = (unsigned short*)(ws + 154 * MB);
    unsigned short* Vb  = (unsigned short*)(ws + 186 * MB);
    unsigned short* Gb  = (unsigned short*)(ws + 218 * MB); // ends at 250 MB
    unsigned short* KF  = (unsigned short*)(ws + 122 * MB); // reuses Rb..Gb (dead after wkv)
    float*          SR  = (float*)(ws + 26 * MB);           // reuses XN (dead)
    float*          X0  = (float*)d_out;                    // residual stream lives in d_out
    float*          Y   = (float*)(ws + 26 * MB);           // wkv out, reuses XN (dead)

    const int NTOK = Bq * Tq;  // 16384
    dim3 g8(8, 128), g28(28, 128);

    // weights -> bf16
    f2bf_kernel<<<1024, blk, 0, stream>>>(aWr, WR);
    f2bf_kernel<<<1024, blk, 0, stream>>>(aWk, WK);
    f2bf_kernel<<<1024, blk, 0, stream>>>(aWv, WV);
    f2bf_kernel<<<1024, blk, 0, stream>>>(aWg, WG);
    f2bf_kernel<<<1024, blk, 0, stream>>>(aWo, WO);
    f2bf_kernel<<<3584, blk, 0, stream>>>(fWk, FWK);
    f2bf_kernel<<<1024, blk, 0, stream>>>(fWr, FWR);
    f2bf_kernel<<<3584, blk, 0, stream>>>(fWv, FWV);

    // ln0 + ln1: x -> X0 (=d_out), xn -> XN
    ln01_kernel<<<NTOK, blk, 0, stream>>>(x, ln0w, ln0b, ln1w, ln1b, X0, XN);

    // time-mix projections (shared MIX buffer, sequential)
    mix1_kernel<<<NTOK, blk, 0, stream>>>(XN, atmr, (ushort4*)MIX);
    gemm_bt<6><<<g8, blk, 0, stream>>>(MIX, WR, Cq, Cq, nullptr, Rb, nullptr, nullptr);
    mix1_kernel<<<NTOK, blk, 0, stream>>>(XN, atmk, (ushort4*)MIX);
    gemm_bt<6><<<g8, blk, 0, stream>>>(MIX, WK, Cq, Cq, nullptr, Kb, nullptr, nullptr);
    mix1_kernel<<<NTOK, blk, 0, stream>>>(XN, atmv, (ushort4*)MIX);
    gemm_bt<6><<<g8, blk, 0, stream>>>(MIX, WV, Cq, Cq, nullptr, Vb, nullptr, nullptr);
    mix1_kernel<<<NTOK, blk, 0, stream>>>(XN, atmg, (ushort4*)MIX);
    gemm_bt<1><<<g8, blk, 0, stream>>>(MIX, WG, Cq, Cq, nullptr, Gb, nullptr, nullptr);

    // chunked wkv recurrence -> Y (xn dead)
    wkv_kernel<<<Bq * Hq, blk, 0, stream>>>(Rb, Kb, Vb, decay, faaaa, Y);
    // groupnorm(y/8)*silu-gate -> Ao (bf16, into MIX)
    gnmul_kernel<<<NTOK, blk, 0, stream>>>(Y, lnxw, lnxb, Gb, (ushort4*)MIX);
    // Wo projection + residual: X0 += Ao @ Wo^T
    gemm_bt<2><<<g8, blk, 0, stream>>>(MIX, WO, Cq, Cq, X0, nullptr, X0, nullptr);

    // channel-mix
    ln_kernel<<<NTOK, blk, 0, stream>>>(X0, ln2w, ln2b, XN);
    mix1_kernel<<<NTOK, blk, 0, stream>>>(XN, ftmk, (ushort4*)MIX);
    gemm_bt<3><<<g28, blk, 0, stream>>>(MIX, FWK, Cq, FFNq, nullptr, KF, nullptr, nullptr);
    mix1_kernel<<<NTOK, blk, 0, stream>>>(XN, ftmr, (ushort4*)MIX);
    gemm_bt<4><<<g8, blk, 0, stream>>>(MIX, FWR, Cq, Cq, SR, nullptr, nullptr, nullptr);
    gemm_bt<5><<<g8, blk, 0, stream>>>(KF, FWV, FFNq, Cq, X0, nullptr, X0, SR);
}

// Round 4
// 1046.413 us; speedup vs baseline: 2.0336x; 1.1032x over previous
//
#include <hip/hip_runtime.h>

#define Bq 8
#define Tq 2048
#define Cq 1024
#define Hq 16
#define Nq 64
#define FFNq 3584
#define EPSq 1e-5f

typedef __bf16 bf8v __attribute__((ext_vector_type(8)));
typedef float f32x4 __attribute__((ext_vector_type(4)));

typedef __attribute__((address_space(1))) const unsigned int GU;
typedef __attribute__((address_space(3))) unsigned int LU;

__device__ __forceinline__ void gload16(const unsigned short* g, unsigned short* l) {
    __builtin_amdgcn_global_load_lds((GU*)g, (LU*)l, 16, 0, 0);
}

__device__ __forceinline__ unsigned short f2bf(float f) {
    unsigned u = __float_as_uint(f);
    u += 0x7fffu + ((u >> 16) & 1u);   // round-to-nearest-even
    return (unsigned short)(u >> 16);
}
__device__ __forceinline__ float bf2f(unsigned short h) {
    return __uint_as_float(((unsigned)h) << 16);
}

// ---------------- diagnostic fill (ws too small) ----------------
__global__ __launch_bounds__(256)
void diag_kernel(float* __restrict__ out, float val) {
    int i = (blockIdx.x * 256 + threadIdx.x) * 4;
    float4 v = make_float4(val, val, val, val);
    *(float4*)(out + i) = v;
}

// ---------------- fp32 -> bf16 weight conversion ----------------
__global__ __launch_bounds__(256)
void f2bf_kernel(const float* __restrict__ in, unsigned short* __restrict__ out) {
    int i = (blockIdx.x * 256 + threadIdx.x) * 4;
    float4 v = *(const float4*)(in + i);
    ushort4 o;
    o.x = f2bf(v.x); o.y = f2bf(v.y); o.z = f2bf(v.z); o.w = f2bf(v.w);
    *(ushort4*)(out + i) = o;
}

// ---------------- block reduction helper (256 threads) ----------------
__device__ __forceinline__ void blockred2(float& a, float& b, float* sm) {
#pragma unroll
    for (int m = 1; m < 64; m <<= 1) { a += __shfl_xor(a, m); b += __shfl_xor(b, m); }
    const int w = threadIdx.x >> 6;
    __syncthreads();
    if ((threadIdx.x & 63) == 0) { sm[w] = a; sm[4 + w] = b; }
    __syncthreads();
    a = sm[0] + sm[1] + sm[2] + sm[3];
    b = sm[4] + sm[5] + sm[6] + sm[7];
}

// ---------------- ln0 + ln1 fused: x -> x0 (fp32), xn (bf16) ----------------
__global__ __launch_bounds__(256)
void ln01_kernel(const float* __restrict__ x,
                 const float* __restrict__ w0, const float* __restrict__ b0,
                 const float* __restrict__ w1, const float* __restrict__ b1,
                 float* __restrict__ x0, unsigned short* __restrict__ xn) {
    __shared__ float sm[8];
    const int tok = blockIdx.x, tid = threadIdx.x, c = tid * 4;
    const size_t base = (size_t)tok * Cq + c;
    float4 v = *(const float4*)(x + base);
    float s = v.x + v.y + v.z + v.w;
    float ss = v.x * v.x + v.y * v.y + v.z * v.z + v.w * v.w;
    blockred2(s, ss, sm);
    float mu = s * (1.f / Cq);
    float rstd = rsqrtf(ss * (1.f / Cq) - mu * mu + EPSq);
    float4 wv = *(const float4*)(w0 + c), bv = *(const float4*)(b0 + c);
    float4 e;
    e.x = (v.x - mu) * rstd * wv.x + bv.x;
    e.y = (v.y - mu) * rstd * wv.y + bv.y;
    e.z = (v.z - mu) * rstd * wv.z + bv.z;
    e.w = (v.w - mu) * rstd * wv.w + bv.w;
    *(float4*)(x0 + base) = e;
    s = e.x + e.y + e.z + e.w;
    ss = e.x * e.x + e.y * e.y + e.z * e.z + e.w * e.w;
    blockred2(s, ss, sm);
    mu = s * (1.f / Cq);
    rstd = rsqrtf(ss * (1.f / Cq) - mu * mu + EPSq);
    wv = *(const float4*)(w1 + c); bv = *(const float4*)(b1 + c);
    ushort4 o;
    o.x = f2bf((e.x - mu) * rstd * wv.x + bv.x);
    o.y = f2bf((e.y - mu) * rstd * wv.y + bv.y);
    o.z = f2bf((e.z - mu) * rstd * wv.z + bv.z);
    o.w = f2bf((e.w - mu) * rstd * wv.w + bv.w);
    *(ushort4*)(xn + base) = o;
}

// ---------------- single layernorm (ln2): fp32 in -> bf16 out ----------------
__global__ __launch_bounds__(256)
void ln_kernel(const float* __restrict__ x, const float* __restrict__ w,
               const float* __restrict__ b, unsigned short* __restrict__ out) {
    __shared__ float sm[8];
    const int tok = blockIdx.x, tid = threadIdx.x, c = tid * 4;
    const size_t base = (size_t)tok * Cq + c;
    float4 v = *(const float4*)(x + base);
    float s = v.x + v.y + v.z + v.w;
    float ss = v.x * v.x + v.y * v.y + v.z * v.z + v.w * v.w;
    blockred2(s, ss, sm);
    float mu = s * (1.f / Cq);
    float rstd = rsqrtf(ss * (1.f / Cq) - mu * mu + EPSq);
    float4 wv = *(const float4*)(w + c), bv = *(const float4*)(b + c);
    ushort4 o;
    o.x = f2bf((v.x - mu) * rstd * wv.x + bv.x);
    o.y = f2bf((v.y - mu) * rstd * wv.y + bv.y);
    o.z = f2bf((v.z - mu) * rstd * wv.z + bv.z);
    o.w = f2bf((v.w - mu) * rstd * wv.w + bv.w);
    *(ushort4*)(out + base) = o;
}

// ---------------- token-shift mix (bf16 xn in, bf16 out) ----------------
__global__ __launch_bounds__(256)
void mix1_kernel(const unsigned short* __restrict__ xn, const float* __restrict__ tm,
                 ushort4* __restrict__ out) {
    const int tok = blockIdx.x, tid = threadIdx.x, c = tid * 4;
    const int t = tok & (Tq - 1);
    const size_t base = (size_t)tok * Cq + c;
    ushort4 a = *(const ushort4*)(xn + base);
    ushort4 p = make_ushort4(0, 0, 0, 0);
    if (t) p = *(const ushort4*)(xn + base - Cq);
    float4 m = *(const float4*)(tm + c);
    ushort4 o;
    float px = bf2f(p.x), py = bf2f(p.y), pz = bf2f(p.z), pw = bf2f(p.w);
    o.x = f2bf(px + m.x * (bf2f(a.x) - px));
    o.y = f2bf(py + m.y * (bf2f(a.y) - py));
    o.z = f2bf(pz + m.z * (bf2f(a.z) - pz));
    o.w = f2bf(pw + m.w * (bf2f(a.w) - pw));
    out[(size_t)tok * 256 + tid] = o;
}

// ---------------- bf16 MFMA GEMM (m97 pattern + group-major swizzle) ----------
// out[m,n] = sum_k A[m,k]*W[n,k]. 1-D grid, GROUP_M=16 m-blocks per group so
// temporally-adjacent blocks share W-tiles (L2 locality).
// MODE: 1 silu->bf16; 2 res+acc->fp32; 3 relu^2->bf16; 4 sigmoid->bf16;
//       5 res+bf2f(sg)*acc->fp32; 6 plain->bf16
template<int MODE>
__global__ __launch_bounds__(256, 2)
void gemm_bt(const unsigned short* __restrict__ A, const unsigned short* __restrict__ W,
             int K, int N, float* __restrict__ outF, unsigned short* __restrict__ outB,
             const float* __restrict__ res, const unsigned short* __restrict__ sg) {
    __shared__ unsigned short As[128 * 32];
    __shared__ unsigned short Bs[128 * 32];
    const int tid = threadIdx.x;
    // group-major swizzle: nm=128 rows of blocks, nn=N/128 cols
    const int nn = N >> 7;
    const int per = nn << 4;            // 16 m-blocks per group
    const int gid = blockIdx.x / per;
    const int rem = blockIdx.x - gid * per;
    const int m0 = ((gid << 4) + (rem & 15)) * 128;
    const int n0 = (rem >> 4) * 128;
    const int wv = tid >> 6, lane = tid & 63;
    const int wm = (wv >> 1) * 64, wn = (wv & 1) * 64;
    const int l15 = lane & 15, q = lane >> 4;

    const int srow = wv * 32 + (lane >> 2);
    const int scol = (lane & 3) * 8;
    const unsigned short* Ag0 = A + (size_t)(m0 + srow) * K + scol;
    const unsigned short* Ag1 = A + (size_t)(m0 + srow + 16) * K + scol;
    const unsigned short* Wg0 = W + (size_t)(n0 + srow) * K + scol;
    const unsigned short* Wg1 = W + (size_t)(n0 + srow + 16) * K + scol;
    unsigned short* As0 = &As[(wv * 32) * 32];
    unsigned short* As1 = &As[(wv * 32 + 16) * 32];
    unsigned short* Bs0 = &Bs[(wv * 32) * 32];
    unsigned short* Bs1 = &Bs[(wv * 32 + 16) * 32];

    f32x4 acc[4][4];
#pragma unroll
    for (int mi = 0; mi < 4; ++mi)
#pragma unroll
        for (int ni = 0; ni < 4; ++ni)
            acc[mi][ni] = {0.f, 0.f, 0.f, 0.f};

    for (int k0 = 0; k0 < K; k0 += 32) {
        gload16(Ag0 + k0, As0);
        gload16(Ag1 + k0, As1);
        gload16(Wg0 + k0, Bs0);
        gload16(Wg1 + k0, Bs1);
        __syncthreads();
        bf8v af[4], bfv[4];
#pragma unroll
        for (int mi = 0; mi < 4; ++mi) af[mi] = *(const bf8v*)&As[(wm + mi * 16 + l15) * 32 + q * 8];
#pragma unroll
        for (int ni = 0; ni < 4; ++ni) bfv[ni] = *(const bf8v*)&Bs[(wn + ni * 16 + l15) * 32 + q * 8];
#pragma unroll
        for (int mi = 0; mi < 4; ++mi)
#pragma unroll
            for (int ni = 0; ni < 4; ++ni)
                acc[mi][ni] = __builtin_amdgcn_mfma_f32_16x16x32_bf16(af[mi], bfv[ni], acc[mi][ni], 0, 0, 0);
        __syncthreads();
    }

#pragma unroll
    for (int mi = 0; mi < 4; ++mi)
#pragma unroll
        for (int ni = 0; ni < 4; ++ni)
#pragma unroll
            for (int j = 0; j < 4; ++j) {
                const int row = m0 + wm + mi * 16 + q * 4 + j;
                const int col = n0 + wn + ni * 16 + l15;
                const size_t idx = (size_t)row * N + col;
                const float a = acc[mi][ni][j];
                if (MODE == 1) {
                    outB[idx] = f2bf(a / (1.f + __expf(-a)));
                } else if (MODE == 2) {
                    outF[idx] = res[idx] + a;
                } else if (MODE == 3) {
                    float t = fmaxf(a, 0.f);
                    outB[idx] = f2bf(t * t);
                } else if (MODE == 4) {
                    outB[idx] = f2bf(1.f / (1.f + __expf(-a)));
                } else if (MODE == 5) {
                    outF[idx] = res[idx] + bf2f(sg[idx]) * a;
                } else {
                    outB[idx] = f2bf(a);
                }
            }
}

// ---------------- WKV5: chunked linear attention + fused GroupNorm*gate ------
// One block per (b,h); 4 waves; chunk L=64; state S (64x64 fp32) in registers.
// Per chunk: A = tril(rp.km^T,-1)+diag(D); Y = A.V + rp.Sc; S = ew^64*S + kd^T.V.
// Epilogue: GroupNorm over the head (intra-wave reduce) * silu-gate -> bf16 Ao.
__global__ __launch_bounds__(256)
void wkv_kernel(const unsigned short* __restrict__ r, const unsigned short* __restrict__ k,
                const unsigned short* __restrict__ v, const unsigned short* __restrict__ g,
                const float* __restrict__ decay, const float* __restrict__ faaaa,
                const float* __restrict__ lnxw, const float* __restrict__ lnxb,
                unsigned short* __restrict__ ao) {
    __shared__ unsigned short rp[64 * 72], km[64 * 72], kdT[64 * 72];
    __shared__ unsigned short VT[64 * 72], Abf[64 * 72], ScT[64 * 72], Gsh[64 * 72];
    __shared__ float Dt[64];
    const int tid = threadIdx.x;
    const int bh = blockIdx.x, b = bh >> 4, h = bh & 15;
    const int tr = tid >> 2, g4 = tid & 3, i0 = g4 * 16;
    const int wv = tid >> 6, lane = tid & 63, l15 = lane & 15, q = lane >> 4;
    const float LOG2E = 1.44269504088896340736f;

    float l2w[16], uu[16];
#pragma unroll
    for (int ii = 0; ii < 16; ++ii) {
        l2w[ii] = -__expf(decay[h * Nq + i0 + ii]) * LOG2E;
        uu[ii] = faaaa[h * Nq + i0 + ii];
    }
    float ewL[4];
#pragma unroll
    for (int jr = 0; jr < 4; ++jr) {
        float lw = -__expf(decay[h * Nq + 16 * wv + q * 4 + jr]) * LOG2E;
        ewL[jr] = exp2f(64.f * lw);
    }
    const int colbase = h * Nq;
    float lwj[4], lbj[4];
#pragma unroll
    for (int nt = 0; nt < 4; ++nt) {
        lwj[nt] = lnxw[colbase + 16 * nt + l15];
        lbj[nt] = lnxb[colbase + 16 * nt + l15];
    }
    f32x4 S[4];
#pragma unroll
    for (int nt = 0; nt < 4; ++nt) S[nt] = {0.f, 0.f, 0.f, 0.f};
    for (int idx = tid; idx < 64 * 72; idx += 256) ScT[idx] = 0;
    __syncthreads();

    const size_t rowbase = (size_t)b * Tq;

    for (int c = 0; c < 32; ++c) {
        // ---- elementwise: load r/k/v/g rows, build scaled operands ----
        const size_t grow = (rowbase + c * 64 + tr) * Cq + colbase + i0;
        unsigned short rs_[16], ks_[16], vs_[16];
        *(uint4*)&rs_[0] = *(const uint4*)(r + grow);
        *(uint4*)&rs_[8] = *(const uint4*)(r + grow + 8);
        *(uint4*)&ks_[0] = *(const uint4*)(k + grow);
        *(uint4*)&ks_[8] = *(const uint4*)(k + grow + 8);
        *(uint4*)&vs_[0] = *(const uint4*)(v + grow);
        *(uint4*)&vs_[8] = *(const uint4*)(v + grow + 8);
        *(uint4*)&Gsh[tr * 72 + i0] = *(const uint4*)(g + grow);
        *(uint4*)&Gsh[tr * 72 + i0 + 8] = *(const uint4*)(g + grow + 8);
        float pd = 0.f;
        const float ftr = (float)tr;
#pragma unroll
        for (int ii = 0; ii < 16; ++ii) {
            float rf = bf2f(rs_[ii]), kf = bf2f(ks_[ii]);
            rp[tr * 72 + i0 + ii] = f2bf(rf * exp2f(ftr * l2w[ii]));
            km[tr * 72 + i0 + ii] = f2bf(kf * exp2f(-(ftr + 1.f) * l2w[ii]));
            kdT[(i0 + ii) * 72 + tr] = f2bf(kf * exp2f((63.f - ftr) * l2w[ii]));
            VT[(i0 + ii) * 72 + tr] = vs_[ii];
            pd += rf * uu[ii] * kf;
        }
        pd += __shfl_xor(pd, 1);
        pd += __shfl_xor(pd, 2);
        if (g4 == 0) Dt[tr] = pd;
        __syncthreads();

        // ---- phase A: A_raw = rp . km^T, mask+diag -> Abf ----
        f32x4 accA[4];
#pragma unroll
        for (int nt = 0; nt < 4; ++nt) accA[nt] = {0.f, 0.f, 0.f, 0.f};
#pragma unroll
        for (int ks = 0; ks < 2; ++ks) {
            bf8v a = *(const bf8v*)&rp[(16 * wv + l15) * 72 + ks * 32 + q * 8];
#pragma unroll
            for (int nt = 0; nt < 4; ++nt) {
                bf8v bb = *(const bf8v*)&km[(16 * nt + l15) * 72 + ks * 32 + q * 8];
                accA[nt] = __builtin_amdgcn_mfma_f32_16x16x32_bf16(a, bb, accA[nt], 0, 0, 0);
            }
        }
#pragma unroll
        for (int nt = 0; nt < 4; ++nt)
#pragma unroll
            for (int jr = 0; jr < 4; ++jr) {
                const int t = 16 * wv + q * 4 + jr, s = 16 * nt + l15;
                const float a = accA[nt][jr];
                const float val = (s < t) ? a : ((s == t) ? Dt[t] : 0.f);
                Abf[t * 72 + s] = f2bf(val);
            }
        // no barrier: each wave reads back exactly the Abf rows it wrote

        // ---- phase B: Y = Abf.V + rp.Sc ----
        f32x4 accY[4];
#pragma unroll
        for (int nt = 0; nt < 4; ++nt) accY[nt] = {0.f, 0.f, 0.f, 0.f};
#pragma unroll
        for (int ks = 0; ks < 2; ++ks) {
            bf8v a = *(const bf8v*)&Abf[(16 * wv + l15) * 72 + ks * 32 + q * 8];
#pragma unroll
            for (int nt = 0; nt < 4; ++nt) {
                bf8v bb = *(const bf8v*)&VT[(16 * nt + l15) * 72 + ks * 32 + q * 8];
                accY[nt] = __builtin_amdgcn_mfma_f32_16x16x32_bf16(a, bb, accY[nt], 0, 0, 0);
            }
        }
#pragma unroll
        for (int ks = 0; ks < 2; ++ks) {
            bf8v a = *(const bf8v*)&rp[(16 * wv + l15) * 72 + ks * 32 + q * 8];
#pragma unroll
            for (int nt = 0; nt < 4; ++nt) {
                bf8v bb = *(const bf8v*)&ScT[(16 * nt + l15) * 72 + ks * 32 + q * 8];
                accY[nt] = __builtin_amdgcn_mfma_f32_16x16x32_bf16(a, bb, accY[nt], 0, 0, 0);
            }
        }

        // ---- fused GroupNorm(y/8)*w+b then *gate -> bf16 Ao ----
        float sum_[4] = {0.f, 0.f, 0.f, 0.f}, sq_[4] = {0.f, 0.f, 0.f, 0.f};
#pragma unroll
        for (int nt = 0; nt < 4; ++nt)
#pragma unroll
            for (int jr = 0; jr < 4; ++jr) {
                float yv = accY[nt][jr] * 0.125f;
                accY[nt][jr] = yv;
                sum_[jr] += yv;
                sq_[jr] += yv * yv;
            }
#pragma unroll
        for (int m = 1; m < 16; m <<= 1)
#pragma unroll
            for (int jr = 0; jr < 4; ++jr) {
                sum_[jr] += __shfl_xor(sum_[jr], m);
                sq_[jr] += __shfl_xor(sq_[jr], m);
            }
        float mu_[4], rstd_[4];
#pragma unroll
        for (int jr = 0; jr < 4; ++jr) {
            mu_[jr] = sum_[jr] * (1.f / Nq);
            rstd_[jr] = rsqrtf(sq_[jr] * (1.f / Nq) - mu_[jr] * mu_[jr] + EPSq);
        }
#pragma unroll
        for (int nt = 0; nt < 4; ++nt)
#pragma unroll
            for (int jr = 0; jr < 4; ++jr) {
                const int t = 16 * wv + q * 4 + jr;
                const float gate = bf2f(Gsh[t * 72 + 16 * nt + l15]);
                const float val = (accY[nt][jr] - mu_[jr]) * rstd_[jr] * lwj[nt] + lbj[nt];
                ao[(rowbase + c * 64 + t) * Cq + colbase + 16 * nt + l15] = f2bf(val * gate);
            }

        // ---- phase C: U = kdT . V ; state update ----
        f32x4 accU[4];
#pragma unroll
        for (int nt = 0; nt < 4; ++nt) accU[nt] = {0.f, 0.f, 0.f, 0.f};
#pragma unroll
        for (int ks = 0; ks < 2; ++ks) {
            bf8v a = *(const bf8v*)&kdT[(16 * wv + l15) * 72 + ks * 32 + q * 8];
#pragma unroll
            for (int nt = 0; nt < 4; ++nt) {
                bf8v bb = *(const bf8v*)&VT[(16 * nt + l15) * 72 + ks * 32 + q * 8];
                accU[nt] = __builtin_amdgcn_mfma_f32_16x16x32_bf16(a, bb, accU[nt], 0, 0, 0);
            }
        }
        __syncthreads();  // all waves done reading ScT/VT before overwrite
#pragma unroll
        for (int nt = 0; nt < 4; ++nt) {
#pragma unroll
            for (int jr = 0; jr < 4; ++jr)
                S[nt][jr] = ewL[jr] * S[nt][jr] + accU[nt][jr];
            ushort4 sc;
            sc.x = f2bf(S[nt][0]); sc.y = f2bf(S[nt][1]);
            sc.z = f2bf(S[nt][2]); sc.w = f2bf(S[nt][3]);
            *(ushort4*)&ScT[(16 * nt + l15) * 72 + 16 * wv + q * 4] = sc;
        }
        __syncthreads();
    }
}

// ---------------- launcher ----------------
extern "C" void kernel_launch(void* const* d_in, const int* in_sizes, int n_in,
                              void* d_out, int out_size, void* d_ws, size_t ws_size,
                              hipStream_t stream) {
    const float* x     = (const float*)d_in[0];
    const float* ln0w  = (const float*)d_in[1];
    const float* ln0b  = (const float*)d_in[2];
    const float* ln1w  = (const float*)d_in[3];
    const float* ln1b  = (const float*)d_in[4];
    const float* ln2w  = (const float*)d_in[5];
    const float* ln2b  = (const float*)d_in[6];
    const float* atmk  = (const float*)d_in[7];
    const float* atmv  = (const float*)d_in[8];
    const float* atmr  = (const float*)d_in[9];
    const float* atmg  = (const float*)d_in[10];
    const float* decay = (const float*)d_in[11];
    const float* faaaa = (const float*)d_in[12];
    const float* aWr   = (const float*)d_in[13];
    const float* aWk   = (const float*)d_in[14];
    const float* aWv   = (const float*)d_in[15];
    const float* aWg   = (const float*)d_in[16];
    const float* aWo   = (const float*)d_in[17];
    const float* lnxw  = (const float*)d_in[18];
    const float* lnxb  = (const float*)d_in[19];
    const float* ftmk  = (const float*)d_in[20];
    const float* ftmr  = (const float*)d_in[21];
    const float* fWk   = (const float*)d_in[22];
    const float* fWr   = (const float*)d_in[23];
    const float* fWv   = (const float*)d_in[24];

    const size_t MB = 1024ull * 1024ull;
    const size_t WS_NEEDED = 250 * MB;
    dim3 blk(256);

    if (ws_size < WS_NEEDED) {
        diag_kernel<<<out_size / 1024, blk, 0, stream>>>((float*)d_out,
            1000.f + (float)((double)ws_size / (double)MB));
        return;
    }

    char* ws = (char*)d_ws;
    // weights (bf16): 26 MB
    unsigned short* WR  = (unsigned short*)(ws + 0 * MB);
    unsigned short* WK  = (unsigned short*)(ws + 2 * MB);
    unsigned short* WV  = (unsigned short*)(ws + 4 * MB);
    unsigned short* WG  = (unsigned short*)(ws + 6 * MB);
    unsigned short* WO  = (unsigned short*)(ws + 8 * MB);
    unsigned short* FWK = (unsigned short*)(ws + 10 * MB);
    unsigned short* FWR = (unsigned short*)(ws + 17 * MB);
    unsigned short* FWV = (unsigned short*)(ws + 19 * MB);
    // activations
    unsigned short* XN  = (unsigned short*)(ws + 26 * MB);  // bf16 xn / xn2
    unsigned short* MIX = (unsigned short*)(ws + 58 * MB);  // mix / Ao (bf16)
    unsigned short* Rb  = (unsigned short*)(ws + 90 * MB);
    unsigned short* Kb  = (unsigned short*)(ws + 122 * MB);
    unsigned short* Vb  = (unsigned short*)(ws + 154 * MB);
    unsigned short* Gb  = (unsigned short*)(ws + 186 * MB); // ends 218 MB
    unsigned short* KF  = (unsigned short*)(ws + 90 * MB);  // 112 MB, reuses Rb..Gb
    unsigned short* SRb = (unsigned short*)(ws + 202 * MB); // 32 MB, ends 234 MB
    float*          X0  = (float*)d_out;                    // residual stream

    const int NTOK = Bq * Tq;  // 16384
    // 1-D swizzled grids: nm=128 m-blocks always
    dim3 g8(8 * 128), g28(28 * 128);

    // weights -> bf16
    f2bf_kernel<<<1024, blk, 0, stream>>>(aWr, WR);
    f2bf_kernel<<<1024, blk, 0, stream>>>(aWk, WK);
    f2bf_kernel<<<1024, blk, 0, stream>>>(aWv, WV);
    f2bf_kernel<<<1024, blk, 0, stream>>>(aWg, WG);
    f2bf_kernel<<<1024, blk, 0, stream>>>(aWo, WO);
    f2bf_kernel<<<3584, blk, 0, stream>>>(fWk, FWK);
    f2bf_kernel<<<1024, blk, 0, stream>>>(fWr, FWR);
    f2bf_kernel<<<3584, blk, 0, stream>>>(fWv, FWV);

    // ln0 + ln1: x -> X0 (=d_out, fp32), xn -> XN (bf16)
    ln01_kernel<<<NTOK, blk, 0, stream>>>(x, ln0w, ln0b, ln1w, ln1b, X0, XN);

    // time-mix projections (shared MIX buffer, sequential)
    mix1_kernel<<<NTOK, blk, 0, stream>>>(XN, atmr, (ushort4*)MIX);
    gemm_bt<6><<<g8, blk, 0, stream>>>(MIX, WR, Cq, Cq, nullptr, Rb, nullptr, nullptr);
    mix1_kernel<<<NTOK, blk, 0, stream>>>(XN, atmk, (ushort4*)MIX);
    gemm_bt<6><<<g8, blk, 0, stream>>>(MIX, WK, Cq, Cq, nullptr, Kb, nullptr, nullptr);
    mix1_kernel<<<NTOK, blk, 0, stream>>>(XN, atmv, (ushort4*)MIX);
    gemm_bt<6><<<g8, blk, 0, stream>>>(MIX, WV, Cq, Cq, nullptr, Vb, nullptr, nullptr);
    mix1_kernel<<<NTOK, blk, 0, stream>>>(XN, atmg, (ushort4*)MIX);
    gemm_bt<1><<<g8, blk, 0, stream>>>(MIX, WG, Cq, Cq, nullptr, Gb, nullptr, nullptr);

    // chunked wkv + fused groupnorm*gate -> Ao (bf16, into MIX)
    wkv_kernel<<<Bq * Hq, blk, 0, stream>>>(Rb, Kb, Vb, Gb, decay, faaaa, lnxw, lnxb, MIX);
    // Wo projection + residual: X0 += Ao @ Wo^T
    gemm_bt<2><<<g8, blk, 0, stream>>>(MIX, WO, Cq, Cq, X0, nullptr, X0, nullptr);

    // channel-mix
    ln_kernel<<<NTOK, blk, 0, stream>>>(X0, ln2w, ln2b, XN);
    mix1_kernel<<<NTOK, blk, 0, stream>>>(XN, ftmk, (ushort4*)MIX);
    gemm_bt<3><<<g28, blk, 0, stream>>>(MIX, FWK, Cq, FFNq, nullptr, KF, nullptr, nullptr);
    mix1_kernel<<<NTOK, blk, 0, stream>>>(XN, ftmr, (ushort4*)MIX);
    gemm_bt<4><<<g8, blk, 0, stream>>>(MIX, FWR, Cq, Cq, nullptr, SRb, nullptr, nullptr);
    gemm_bt<5><<<g8, blk, 0, stream>>>(KF, FWV, FFNq, Cq, X0, nullptr, X0, SRb);
}

// Round 5
// 973.424 us; speedup vs baseline: 2.1861x; 1.0750x over previous
//
#include <hip/hip_runtime.h>

#define Bq 8
#define Tq 2048
#define Cq 1024
#define Hq 16
#define Nq 64
#define FFNq 3584
#define EPSq 1e-5f

typedef __bf16 bf8v __attribute__((ext_vector_type(8)));
typedef float f32x4 __attribute__((ext_vector_type(4)));

typedef __attribute__((address_space(1))) const unsigned int GU;
typedef __attribute__((address_space(3))) unsigned int LU;

__device__ __forceinline__ void gload16(const unsigned short* g, unsigned short* l) {
    __builtin_amdgcn_global_load_lds((GU*)g, (LU*)l, 16, 0, 0);
}

__device__ __forceinline__ unsigned short f2bf(float f) {
    unsigned u = __float_as_uint(f);
    u += 0x7fffu + ((u >> 16) & 1u);   // round-to-nearest-even
    return (unsigned short)(u >> 16);
}
__device__ __forceinline__ float bf2f(unsigned short h) {
    return __uint_as_float(((unsigned)h) << 16);
}

// ---------------- diagnostic fill (ws too small) ----------------
__global__ __launch_bounds__(256)
void diag_kernel(float* __restrict__ out, float val) {
    int i = (blockIdx.x * 256 + threadIdx.x) * 4;
    float4 v = make_float4(val, val, val, val);
    *(float4*)(out + i) = v;
}

// ---------------- fp32 -> bf16 conversion, all 8 weights in one launch -------
// segments (in 256-thread*4-elem blocks): 5x1024 (WR,WK,WV,WG,WO), 3584 (FWK),
// 1024 (FWR), 3584 (FWV). total 13312 blocks.
__global__ __launch_bounds__(256)
void f2bf_all_kernel(const float* __restrict__ s0, const float* __restrict__ s1,
                     const float* __restrict__ s2, const float* __restrict__ s3,
                     const float* __restrict__ s4, const float* __restrict__ s5,
                     const float* __restrict__ s6, const float* __restrict__ s7,
                     unsigned short* __restrict__ d0, unsigned short* __restrict__ d1,
                     unsigned short* __restrict__ d2, unsigned short* __restrict__ d3,
                     unsigned short* __restrict__ d4, unsigned short* __restrict__ d5,
                     unsigned short* __restrict__ d6, unsigned short* __restrict__ d7) {
    int b = blockIdx.x;
    const float* src; unsigned short* dst;
    if      (b < 1024)  { src = s0; dst = d0; }
    else if (b < 2048)  { src = s1; dst = d1; b -= 1024; }
    else if (b < 3072)  { src = s2; dst = d2; b -= 2048; }
    else if (b < 4096)  { src = s3; dst = d3; b -= 3072; }
    else if (b < 5120)  { src = s4; dst = d4; b -= 4096; }
    else if (b < 8704)  { src = s5; dst = d5; b -= 5120; }
    else if (b < 9728)  { src = s6; dst = d6; b -= 8704; }
    else                { src = s7; dst = d7; b -= 9728; }
    int i = (b * 256 + threadIdx.x) * 4;
    float4 v = *(const float4*)(src + i);
    ushort4 o;
    o.x = f2bf(v.x); o.y = f2bf(v.y); o.z = f2bf(v.z); o.w = f2bf(v.w);
    *(ushort4*)(dst + i) = o;
}

// ---------------- block reduction helper (256 threads) ----------------
__device__ __forceinline__ void blockred2(float& a, float& b, float* sm) {
#pragma unroll
    for (int m = 1; m < 64; m <<= 1) { a += __shfl_xor(a, m); b += __shfl_xor(b, m); }
    const int w = threadIdx.x >> 6;
    __syncthreads();
    if ((threadIdx.x & 63) == 0) { sm[w] = a; sm[4 + w] = b; }
    __syncthreads();
    a = sm[0] + sm[1] + sm[2] + sm[3];
    b = sm[4] + sm[5] + sm[6] + sm[7];
}

// ---------------- ln0 + ln1 fused: x -> x0 (fp32), xn (bf16) ----------------
__global__ __launch_bounds__(256)
void ln01_kernel(const float* __restrict__ x,
                 const float* __restrict__ w0, const float* __restrict__ b0,
                 const float* __restrict__ w1, const float* __restrict__ b1,
                 float* __restrict__ x0, unsigned short* __restrict__ xn) {
    __shared__ float sm[8];
    const int tok = blockIdx.x, tid = threadIdx.x, c = tid * 4;
    const size_t base = (size_t)tok * Cq + c;
    float4 v = *(const float4*)(x + base);
    float s = v.x + v.y + v.z + v.w;
    float ss = v.x * v.x + v.y * v.y + v.z * v.z + v.w * v.w;
    blockred2(s, ss, sm);
    float mu = s * (1.f / Cq);
    float rstd = rsqrtf(ss * (1.f / Cq) - mu * mu + EPSq);
    float4 wv = *(const float4*)(w0 + c), bv = *(const float4*)(b0 + c);
    float4 e;
    e.x = (v.x - mu) * rstd * wv.x + bv.x;
    e.y = (v.y - mu) * rstd * wv.y + bv.y;
    e.z = (v.z - mu) * rstd * wv.z + bv.z;
    e.w = (v.w - mu) * rstd * wv.w + bv.w;
    *(float4*)(x0 + base) = e;
    s = e.x + e.y + e.z + e.w;
    ss = e.x * e.x + e.y * e.y + e.z * e.z + e.w * e.w;
    blockred2(s, ss, sm);
    mu = s * (1.f / Cq);
    rstd = rsqrtf(ss * (1.f / Cq) - mu * mu + EPSq);
    wv = *(const float4*)(w1 + c); bv = *(const float4*)(b1 + c);
    ushort4 o;
    o.x = f2bf((e.x - mu) * rstd * wv.x + bv.x);
    o.y = f2bf((e.y - mu) * rstd * wv.y + bv.y);
    o.z = f2bf((e.z - mu) * rstd * wv.z + bv.z);
    o.w = f2bf((e.w - mu) * rstd * wv.w + bv.w);
    *(ushort4*)(xn + base) = o;
}

// ---------------- single layernorm (ln2): fp32 in -> bf16 out ----------------
__global__ __launch_bounds__(256)
void ln_kernel(const float* __restrict__ x, const float* __restrict__ w,
               const float* __restrict__ b, unsigned short* __restrict__ out) {
    __shared__ float sm[8];
    const int tok = blockIdx.x, tid = threadIdx.x, c = tid * 4;
    const size_t base = (size_t)tok * Cq + c;
    float4 v = *(const float4*)(x + base);
    float s = v.x + v.y + v.z + v.w;
    float ss = v.x * v.x + v.y * v.y + v.z * v.z + v.w * v.w;
    blockred2(s, ss, sm);
    float mu = s * (1.f / Cq);
    float rstd = rsqrtf(ss * (1.f / Cq) - mu * mu + EPSq);
    float4 wv = *(const float4*)(w + c), bv = *(const float4*)(b + c);
    ushort4 o;
    o.x = f2bf((v.x - mu) * rstd * wv.x + bv.x);
    o.y = f2bf((v.y - mu) * rstd * wv.y + bv.y);
    o.z = f2bf((v.z - mu) * rstd * wv.z + bv.z);
    o.w = f2bf((v.w - mu) * rstd * wv.w + bv.w);
    *(ushort4*)(out + base) = o;
}

// ---------------- token-shift: 4 mixes in one pass (time-mix) ----------------
__device__ __forceinline__ ushort4 mixpack(float ax, float ay, float az, float aw,
                                           float px, float py, float pz, float pw,
                                           const float4& m) {
    ushort4 o;
    o.x = f2bf(px + m.x * (ax - px));
    o.y = f2bf(py + m.y * (ay - py));
    o.z = f2bf(pz + m.z * (az - pz));
    o.w = f2bf(pw + m.w * (aw - pw));
    return o;
}

__global__ __launch_bounds__(256)
void mix4_kernel(const unsigned short* __restrict__ xn,
                 const float* __restrict__ tmr, const float* __restrict__ tmk,
                 const float* __restrict__ tmv, const float* __restrict__ tmg,
                 ushort4* __restrict__ outR, ushort4* __restrict__ outK,
                 ushort4* __restrict__ outV, ushort4* __restrict__ outG) {
    const int tok = blockIdx.x, tid = threadIdx.x, c = tid * 4;
    const int t = tok & (Tq - 1);
    const size_t base = (size_t)tok * Cq + c;
    ushort4 a = *(const ushort4*)(xn + base);
    ushort4 p = make_ushort4(0, 0, 0, 0);
    if (t) p = *(const ushort4*)(xn + base - Cq);
    float ax = bf2f(a.x), ay = bf2f(a.y), az = bf2f(a.z), aw = bf2f(a.w);
    float px = bf2f(p.x), py = bf2f(p.y), pz = bf2f(p.z), pw = bf2f(p.w);
    const size_t b4 = (size_t)tok * 256 + tid;
    outR[b4] = mixpack(ax, ay, az, aw, px, py, pz, pw, *(const float4*)(tmr + c));
    outK[b4] = mixpack(ax, ay, az, aw, px, py, pz, pw, *(const float4*)(tmk + c));
    outV[b4] = mixpack(ax, ay, az, aw, px, py, pz, pw, *(const float4*)(tmv + c));
    outG[b4] = mixpack(ax, ay, az, aw, px, py, pz, pw, *(const float4*)(tmg + c));
}

// ---------------- token-shift: 2 mixes in one pass (channel-mix) -------------
__global__ __launch_bounds__(256)
void mix2_kernel(const unsigned short* __restrict__ xn,
                 const float* __restrict__ tmk, const float* __restrict__ tmr,
                 ushort4* __restrict__ outK, ushort4* __restrict__ outR) {
    const int tok = blockIdx.x, tid = threadIdx.x, c = tid * 4;
    const int t = tok & (Tq - 1);
    const size_t base = (size_t)tok * Cq + c;
    ushort4 a = *(const ushort4*)(xn + base);
    ushort4 p = make_ushort4(0, 0, 0, 0);
    if (t) p = *(const ushort4*)(xn + base - Cq);
    float ax = bf2f(a.x), ay = bf2f(a.y), az = bf2f(a.z), aw = bf2f(a.w);
    float px = bf2f(p.x), py = bf2f(p.y), pz = bf2f(p.z), pw = bf2f(p.w);
    const size_t b4 = (size_t)tok * 256 + tid;
    outK[b4] = mixpack(ax, ay, az, aw, px, py, pz, pw, *(const float4*)(tmk + c));
    outR[b4] = mixpack(ax, ay, az, aw, px, py, pz, pw, *(const float4*)(tmr + c));
}

// ---------------- bf16 MFMA GEMM (m97 pattern + group-major swizzle) ----------
// out[m,n] = sum_k A[m,k]*W[n,k]. 1-D grid, GROUP_M=16 m-blocks per group so
// temporally-adjacent blocks share W-tiles (L2 locality).
// MODE: 1 silu->bf16; 2 res+acc->fp32; 3 relu^2->bf16; 4 sigmoid->bf16;
//       5 res+bf2f(sg)*acc->fp32; 6 plain->bf16
template<int MODE>
__global__ __launch_bounds__(256, 2)
void gemm_bt(const unsigned short* __restrict__ A, const unsigned short* __restrict__ W,
             int K, int N, float* __restrict__ outF, unsigned short* __restrict__ outB,
             const float* __restrict__ res, const unsigned short* __restrict__ sg) {
    __shared__ unsigned short As[128 * 32];
    __shared__ unsigned short Bs[128 * 32];
    const int tid = threadIdx.x;
    const int nn = N >> 7;
    const int per = nn << 4;            // 16 m-blocks per group
    const int gid = blockIdx.x / per;
    const int rem = blockIdx.x - gid * per;
    const int m0 = ((gid << 4) + (rem & 15)) * 128;
    const int n0 = (rem >> 4) * 128;
    const int wv = tid >> 6, lane = tid & 63;
    const int wm = (wv >> 1) * 64, wn = (wv & 1) * 64;
    const int l15 = lane & 15, q = lane >> 4;

    const int srow = wv * 32 + (lane >> 2);
    const int scol = (lane & 3) * 8;
    const unsigned short* Ag0 = A + (size_t)(m0 + srow) * K + scol;
    const unsigned short* Ag1 = A + (size_t)(m0 + srow + 16) * K + scol;
    const unsigned short* Wg0 = W + (size_t)(n0 + srow) * K + scol;
    const unsigned short* Wg1 = W + (size_t)(n0 + srow + 16) * K + scol;
    unsigned short* As0 = &As[(wv * 32) * 32];
    unsigned short* As1 = &As[(wv * 32 + 16) * 32];
    unsigned short* Bs0 = &Bs[(wv * 32) * 32];
    unsigned short* Bs1 = &Bs[(wv * 32 + 16) * 32];

    f32x4 acc[4][4];
#pragma unroll
    for (int mi = 0; mi < 4; ++mi)
#pragma unroll
        for (int ni = 0; ni < 4; ++ni)
            acc[mi][ni] = {0.f, 0.f, 0.f, 0.f};

    for (int k0 = 0; k0 < K; k0 += 32) {
        gload16(Ag0 + k0, As0);
        gload16(Ag1 + k0, As1);
        gload16(Wg0 + k0, Bs0);
        gload16(Wg1 + k0, Bs1);
        __syncthreads();
        bf8v af[4], bfv[4];
#pragma unroll
        for (int mi = 0; mi < 4; ++mi) af[mi] = *(const bf8v*)&As[(wm + mi * 16 + l15) * 32 + q * 8];
#pragma unroll
        for (int ni = 0; ni < 4; ++ni) bfv[ni] = *(const bf8v*)&Bs[(wn + ni * 16 + l15) * 32 + q * 8];
#pragma unroll
        for (int mi = 0; mi < 4; ++mi)
#pragma unroll
            for (int ni = 0; ni < 4; ++ni)
                acc[mi][ni] = __builtin_amdgcn_mfma_f32_16x16x32_bf16(af[mi], bfv[ni], acc[mi][ni], 0, 0, 0);
        __syncthreads();
    }

#pragma unroll
    for (int mi = 0; mi < 4; ++mi)
#pragma unroll
        for (int ni = 0; ni < 4; ++ni)
#pragma unroll
            for (int j = 0; j < 4; ++j) {
                const int row = m0 + wm + mi * 16 + q * 4 + j;
                const int col = n0 + wn + ni * 16 + l15;
                const size_t idx = (size_t)row * N + col;
                const float a = acc[mi][ni][j];
                if (MODE == 1) {
                    outB[idx] = f2bf(a / (1.f + __expf(-a)));
                } else if (MODE == 2) {
                    outF[idx] = res[idx] + a;
                } else if (MODE == 3) {
                    float t = fmaxf(a, 0.f);
                    outB[idx] = f2bf(t * t);
                } else if (MODE == 4) {
                    outB[idx] = f2bf(1.f / (1.f + __expf(-a)));
                } else if (MODE == 5) {
                    outF[idx] = res[idx] + bf2f(sg[idx]) * a;
                } else {
                    outB[idx] = f2bf(a);
                }
            }
}

// ---------------- WKV5: chunked linear attention + fused GroupNorm*gate ------
// One block per (b,h); 4 waves; chunk L=64; state S (64x64 fp32) in registers.
// Per chunk: A = tril(rp.km^T,-1)+diag(D); Y = A.V + rp.Sc; S = ew^64*S + kd^T.V.
// Epilogue: GroupNorm over the head (intra-wave reduce) * silu-gate -> bf16 Ao.
__global__ __launch_bounds__(256)
void wkv_kernel(const unsigned short* __restrict__ r, const unsigned short* __restrict__ k,
                const unsigned short* __restrict__ v, const unsigned short* __restrict__ g,
                const float* __restrict__ decay, const float* __restrict__ faaaa,
                const float* __restrict__ lnxw, const float* __restrict__ lnxb,
                unsigned short* __restrict__ ao) {
    __shared__ unsigned short rp[64 * 72], km[64 * 72], kdT[64 * 72];
    __shared__ unsigned short VT[64 * 72], Abf[64 * 72], ScT[64 * 72], Gsh[64 * 72];
    __shared__ float Dt[64];
    const int tid = threadIdx.x;
    const int bh = blockIdx.x, b = bh >> 4, h = bh & 15;
    const int tr = tid >> 2, g4 = tid & 3, i0 = g4 * 16;
    const int wv = tid >> 6, lane = tid & 63, l15 = lane & 15, q = lane >> 4;
    const float LOG2E = 1.44269504088896340736f;

    float l2w[16], uu[16];
#pragma unroll
    for (int ii = 0; ii < 16; ++ii) {
        l2w[ii] = -__expf(decay[h * Nq + i0 + ii]) * LOG2E;
        uu[ii] = faaaa[h * Nq + i0 + ii];
    }
    float ewL[4];
#pragma unroll
    for (int jr = 0; jr < 4; ++jr) {
        float lw = -__expf(decay[h * Nq + 16 * wv + q * 4 + jr]) * LOG2E;
        ewL[jr] = exp2f(64.f * lw);
    }
    const int colbase = h * Nq;
    float lwj[4], lbj[4];
#pragma unroll
    for (int nt = 0; nt < 4; ++nt) {
        lwj[nt] = lnxw[colbase + 16 * nt + l15];
        lbj[nt] = lnxb[colbase + 16 * nt + l15];
    }
    f32x4 S[4];
#pragma unroll
    for (int nt = 0; nt < 4; ++nt) S[nt] = {0.f, 0.f, 0.f, 0.f};
    for (int idx = tid; idx < 64 * 72; idx += 256) ScT[idx] = 0;
    __syncthreads();

    const size_t rowbase = (size_t)b * Tq;

    for (int c = 0; c < 32; ++c) {
        // ---- elementwise: load r/k/v/g rows, build scaled operands ----
        const size_t grow = (rowbase + c * 64 + tr) * Cq + colbase + i0;
        unsigned short rs_[16], ks_[16], vs_[16];
        *(uint4*)&rs_[0] = *(const uint4*)(r + grow);
        *(uint4*)&rs_[8] = *(const uint4*)(r + grow + 8);
        *(uint4*)&ks_[0] = *(const uint4*)(k + grow);
        *(uint4*)&ks_[8] = *(const uint4*)(k + grow + 8);
        *(uint4*)&vs_[0] = *(const uint4*)(v + grow);
        *(uint4*)&vs_[8] = *(const uint4*)(v + grow + 8);
        *(uint4*)&Gsh[tr * 72 + i0] = *(const uint4*)(g + grow);
        *(uint4*)&Gsh[tr * 72 + i0 + 8] = *(const uint4*)(g + grow + 8);
        float pd = 0.f;
        const float ftr = (float)tr;
#pragma unroll
        for (int ii = 0; ii < 16; ++ii) {
            float rf = bf2f(rs_[ii]), kf = bf2f(ks_[ii]);
            rp[tr * 72 + i0 + ii] = f2bf(rf * exp2f(ftr * l2w[ii]));
            km[tr * 72 + i0 + ii] = f2bf(kf * exp2f(-(ftr + 1.f) * l2w[ii]));
            kdT[(i0 + ii) * 72 + tr] = f2bf(kf * exp2f((63.f - ftr) * l2w[ii]));
            VT[(i0 + ii) * 72 + tr] = vs_[ii];
            pd += rf * uu[ii] * kf;
        }
        pd += __shfl_xor(pd, 1);
        pd += __shfl_xor(pd, 2);
        if (g4 == 0) Dt[tr] = pd;
        __syncthreads();

        // ---- phase A: A_raw = rp . km^T, mask+diag -> Abf ----
        f32x4 accA[4];
#pragma unroll
        for (int nt = 0; nt < 4; ++nt) accA[nt] = {0.f, 0.f, 0.f, 0.f};
#pragma unroll
        for (int ks = 0; ks < 2; ++ks) {
            bf8v a = *(const bf8v*)&rp[(16 * wv + l15) * 72 + ks * 32 + q * 8];
#pragma unroll
            for (int nt = 0; nt < 4; ++nt) {
                bf8v bb = *(const bf8v*)&km[(16 * nt + l15) * 72 + ks * 32 + q * 8];
                accA[nt] = __builtin_amdgcn_mfma_f32_16x16x32_bf16(a, bb, accA[nt], 0, 0, 0);
            }
        }
#pragma unroll
        for (int nt = 0; nt < 4; ++nt)
#pragma unroll
            for (int jr = 0; jr < 4; ++jr) {
                const int t = 16 * wv + q * 4 + jr, s = 16 * nt + l15;
                const float a = accA[nt][jr];
                const float val = (s < t) ? a : ((s == t) ? Dt[t] : 0.f);
                Abf[t * 72 + s] = f2bf(val);
            }
        // no barrier: each wave reads back exactly the Abf rows it wrote

        // ---- phase B: Y = Abf.V + rp.Sc ----
        f32x4 accY[4];
#pragma unroll
        for (int nt = 0; nt < 4; ++nt) accY[nt] = {0.f, 0.f, 0.f, 0.f};
#pragma unroll
        for (int ks = 0; ks < 2; ++ks) {
            bf8v a = *(const bf8v*)&Abf[(16 * wv + l15) * 72 + ks * 32 + q * 8];
#pragma unroll
            for (int nt = 0; nt < 4; ++nt) {
                bf8v bb = *(const bf8v*)&VT[(16 * nt + l15) * 72 + ks * 32 + q * 8];
                accY[nt] = __builtin_amdgcn_mfma_f32_16x16x32_bf16(a, bb, accY[nt], 0, 0, 0);
            }
        }
#pragma unroll
        for (int ks = 0; ks < 2; ++ks) {
            bf8v a = *(const bf8v*)&rp[(16 * wv + l15) * 72 + ks * 32 + q * 8];
#pragma unroll
            for (int nt = 0; nt < 4; ++nt) {
                bf8v bb = *(const bf8v*)&ScT[(16 * nt + l15) * 72 + ks * 32 + q * 8];
                accY[nt] = __builtin_amdgcn_mfma_f32_16x16x32_bf16(a, bb, accY[nt], 0, 0, 0);
            }
        }

        // ---- fused GroupNorm(y/8)*w+b then *gate -> bf16 Ao ----
        float sum_[4] = {0.f, 0.f, 0.f, 0.f}, sq_[4] = {0.f, 0.f, 0.f, 0.f};
#pragma unroll
        for (int nt = 0; nt < 4; ++nt)
#pragma unroll
            for (int jr = 0; jr < 4; ++jr) {
                float yv = accY[nt][jr] * 0.125f;
                accY[nt][jr] = yv;
                sum_[jr] += yv;
                sq_[jr] += yv * yv;
            }
#pragma unroll
        for (int m = 1; m < 16; m <<= 1)
#pragma unroll
            for (int jr = 0; jr < 4; ++jr) {
                sum_[jr] += __shfl_xor(sum_[jr], m);
                sq_[jr] += __shfl_xor(sq_[jr], m);
            }
        float mu_[4], rstd_[4];
#pragma unroll
        for (int jr = 0; jr < 4; ++jr) {
            mu_[jr] = sum_[jr] * (1.f / Nq);
            rstd_[jr] = rsqrtf(sq_[jr] * (1.f / Nq) - mu_[jr] * mu_[jr] + EPSq);
        }
#pragma unroll
        for (int nt = 0; nt < 4; ++nt)
#pragma unroll
            for (int jr = 0; jr < 4; ++jr) {
                const int t = 16 * wv + q * 4 + jr;
                const float gate = bf2f(Gsh[t * 72 + 16 * nt + l15]);
                const float val = (accY[nt][jr] - mu_[jr]) * rstd_[jr] * lwj[nt] + lbj[nt];
                ao[(rowbase + c * 64 + t) * Cq + colbase + 16 * nt + l15] = f2bf(val * gate);
            }

        // ---- phase C: U = kdT . V ; state update ----
        f32x4 accU[4];
#pragma unroll
        for (int nt = 0; nt < 4; ++nt) accU[nt] = {0.f, 0.f, 0.f, 0.f};
#pragma unroll
        for (int ks = 0; ks < 2; ++ks) {
            bf8v a = *(const bf8v*)&kdT[(16 * wv + l15) * 72 + ks * 32 + q * 8];
#pragma unroll
            for (int nt = 0; nt < 4; ++nt) {
                bf8v bb = *(const bf8v*)&VT[(16 * nt + l15) * 72 + ks * 32 + q * 8];
                accU[nt] = __builtin_amdgcn_mfma_f32_16x16x32_bf16(a, bb, accU[nt], 0, 0, 0);
            }
        }
        __syncthreads();  // all waves done reading ScT/VT before overwrite
#pragma unroll
        for (int nt = 0; nt < 4; ++nt) {
#pragma unroll
            for (int jr = 0; jr < 4; ++jr)
                S[nt][jr] = ewL[jr] * S[nt][jr] + accU[nt][jr];
            ushort4 sc;
            sc.x = f2bf(S[nt][0]); sc.y = f2bf(S[nt][1]);
            sc.z = f2bf(S[nt][2]); sc.w = f2bf(S[nt][3]);
            *(ushort4*)&ScT[(16 * nt + l15) * 72 + 16 * wv + q * 4] = sc;
        }
        __syncthreads();
    }
}

// ---------------- launcher ----------------
extern "C" void kernel_launch(void* const* d_in, const int* in_sizes, int n_in,
                              void* d_out, int out_size, void* d_ws, size_t ws_size,
                              hipStream_t stream) {
    const float* x     = (const float*)d_in[0];
    const float* ln0w  = (const float*)d_in[1];
    const float* ln0b  = (const float*)d_in[2];
    const float* ln1w  = (const float*)d_in[3];
    const float* ln1b  = (const float*)d_in[4];
    const float* ln2w  = (const float*)d_in[5];
    const float* ln2b  = (const float*)d_in[6];
    const float* atmk  = (const float*)d_in[7];
    const float* atmv  = (const float*)d_in[8];
    const float* atmr  = (const float*)d_in[9];
    const float* atmg  = (const float*)d_in[10];
    const float* decay = (const float*)d_in[11];
    const float* faaaa = (const float*)d_in[12];
    const float* aWr   = (const float*)d_in[13];
    const float* aWk   = (const float*)d_in[14];
    const float* aWv   = (const float*)d_in[15];
    const float* aWg   = (const float*)d_in[16];
    const float* aWo   = (const float*)d_in[17];
    const float* lnxw  = (const float*)d_in[18];
    const float* lnxb  = (const float*)d_in[19];
    const float* ftmk  = (const float*)d_in[20];
    const float* ftmr  = (const float*)d_in[21];
    const float* fWk   = (const float*)d_in[22];
    const float* fWr   = (const float*)d_in[23];
    const float* fWv   = (const float*)d_in[24];

    const size_t MB = 1024ull * 1024ull;
    const size_t WS_NEEDED = 250 * MB;
    dim3 blk(256);

    if (ws_size < WS_NEEDED) {
        diag_kernel<<<out_size / 1024, blk, 0, stream>>>((float*)d_out,
            1000.f + (float)((double)ws_size / (double)MB));
        return;
    }

    char* ws = (char*)d_ws;
    // weights (bf16): 26 MB
    unsigned short* WR  = (unsigned short*)(ws + 0 * MB);
    unsigned short* WK  = (unsigned short*)(ws + 2 * MB);
    unsigned short* WV  = (unsigned short*)(ws + 4 * MB);
    unsigned short* WG  = (unsigned short*)(ws + 6 * MB);
    unsigned short* WO  = (unsigned short*)(ws + 8 * MB);
    unsigned short* FWK = (unsigned short*)(ws + 10 * MB);
    unsigned short* FWR = (unsigned short*)(ws + 17 * MB);
    unsigned short* FWV = (unsigned short*)(ws + 19 * MB);
    // activation schedule (aliased; all bf16 except X0):
    unsigned short* XN  = (unsigned short*)(ws + 26 * MB);  // xn (dead after mix4) / xn2
    unsigned short* MXR = (unsigned short*)(ws + 58 * MB);
    unsigned short* MXK = (unsigned short*)(ws + 90 * MB);
    unsigned short* MXV = (unsigned short*)(ws + 122 * MB);
    unsigned short* MXG = (unsigned short*)(ws + 154 * MB);
    unsigned short* Rb  = (unsigned short*)(ws + 186 * MB); // ..218
    unsigned short* Kb  = (unsigned short*)(ws + 58 * MB);  // reuses MXR (dead)
    unsigned short* Vb  = (unsigned short*)(ws + 90 * MB);  // reuses MXK (dead)
    unsigned short* Gb  = (unsigned short*)(ws + 122 * MB); // reuses MXV (dead)
    unsigned short* AO  = (unsigned short*)(ws + 154 * MB); // reuses MXG (dead)
    unsigned short* XK2 = (unsigned short*)(ws + 58 * MB);  // reuses Kb (dead)
    unsigned short* XR2 = (unsigned short*)(ws + 90 * MB);  // reuses Vb (dead)
    unsigned short* KF  = (unsigned short*)(ws + 122 * MB); // 112 MB ..234 (Gb/AO/Rb dead)
    unsigned short* SRb = (unsigned short*)(ws + 26 * MB);  // reuses XN (dead)
    float*          X0  = (float*)d_out;                    // residual stream

    const int NTOK = Bq * Tq;  // 16384
    dim3 g8(8 * 128), g28(28 * 128);

    // all weights -> bf16 in one launch
    f2bf_all_kernel<<<13312, blk, 0, stream>>>(aWr, aWk, aWv, aWg, aWo, fWk, fWr, fWv,
                                               WR, WK, WV, WG, WO, FWK, FWR, FWV);

    // ln0 + ln1: x -> X0 (=d_out, fp32), xn -> XN (bf16)
    ln01_kernel<<<NTOK, blk, 0, stream>>>(x, ln0w, ln0b, ln1w, ln1b, X0, XN);

    // time-mix token shift: all four branches in one pass
    mix4_kernel<<<NTOK, blk, 0, stream>>>(XN, atmr, atmk, atmv, atmg,
                                          (ushort4*)MXR, (ushort4*)MXK,
                                          (ushort4*)MXV, (ushort4*)MXG);
    // projections (outputs alias consumed mix buffers)
    gemm_bt<6><<<g8, blk, 0, stream>>>(MXR, WR, Cq, Cq, nullptr, Rb, nullptr, nullptr);
    gemm_bt<6><<<g8, blk, 0, stream>>>(MXK, WK, Cq, Cq, nullptr, Kb, nullptr, nullptr);
    gemm_bt<6><<<g8, blk, 0, stream>>>(MXV, WV, Cq, Cq, nullptr, Vb, nullptr, nullptr);
    gemm_bt<1><<<g8, blk, 0, stream>>>(MXG, WG, Cq, Cq, nullptr, Gb, nullptr, nullptr);

    // chunked wkv + fused groupnorm*gate -> AO (bf16)
    wkv_kernel<<<Bq * Hq, blk, 0, stream>>>(Rb, Kb, Vb, Gb, decay, faaaa, lnxw, lnxb, AO);
    // Wo projection + residual: X0 += AO @ Wo^T
    gemm_bt<2><<<g8, blk, 0, stream>>>(AO, WO, Cq, Cq, X0, nullptr, X0, nullptr);

    // channel-mix
    ln_kernel<<<NTOK, blk, 0, stream>>>(X0, ln2w, ln2b, XN);
    mix2_kernel<<<NTOK, blk, 0, stream>>>(XN, ftmk, ftmr, (ushort4*)XK2, (ushort4*)XR2);
    gemm_bt<3><<<g28, blk, 0, stream>>>(XK2, FWK, Cq, FFNq, nullptr, KF, nullptr, nullptr);
    gemm_bt<4><<<g8, blk, 0, stream>>>(XR2, FWR, Cq, Cq, nullptr, SRb, nullptr, nullptr);
    gemm_bt<5><<<g8, blk, 0, stream>>>(KF, FWV, FFNq, Cq, X0, nullptr, X0, SRb);
}